// Round 4
// baseline (901.231 us; speedup 1.0000x reference)
//
#include <hip/hip_runtime.h>

#define Hh 51
#define TT 512
#define MROW 8          // batch rows per block
#define NBLK 64         // 512 / MROW
#define BT 512          // 8 waves
#define SZ 217          // Z row stride (floats), odd, >= 217 to keep lane reads in-row
#define SH 72           // H-split row stride (bf16 elems): 144B rows -> 2-way (free) on b128
#define SX 9            // xs / ob stride (floats), odd -> conflict-free staging
#define LOG2E 1.4426950408889634f

typedef __attribute__((ext_vector_type(8))) short bf16x8;
typedef __attribute__((ext_vector_type(4))) float f32x4;

__device__ __forceinline__ float fexp2(float x){ return __builtin_amdgcn_exp2f(x); }
__device__ __forceinline__ float frcp(float x){ return __builtin_amdgcn_rcpf(x); }
__device__ __forceinline__ float sigm(float x){ return frcp(1.f + fexp2(-LOG2E*x)); }
__device__ __forceinline__ float ftanh(float x){ return 1.f - 2.f*frcp(1.f + fexp2(2.f*LOG2E*x)); }
__device__ __forceinline__ short topb(float v){ return (short)(__float_as_uint(v)>>16); }
__device__ __forceinline__ float topf(float v){ return __uint_as_float(__float_as_uint(v)&0xFFFF0000u); }

#define MFMA(a,b,c) __builtin_amdgcn_mfma_f32_16x16x32_bf16(a,b,c,0,0,0)

__global__ __launch_bounds__(BT, 2) void lstm2_mfma(
    const float* __restrict__ input,   // [512,512]
    const float* __restrict__ W_ih1,   // [204]
    const float* __restrict__ W_hh1,   // [204,51]
    const float* __restrict__ b_ih1,
    const float* __restrict__ b_hh1,
    const float* __restrict__ W_ih2,   // [204,51]
    const float* __restrict__ W_hh2,   // [204,51]
    const float* __restrict__ b_ih2,
    const float* __restrict__ b_hh2,
    const float* __restrict__ W_lin,   // [51]
    const float* __restrict__ b_lin,   // [1]
    float* __restrict__ out)           // [512,512]
{
    __shared__ float xs[TT*SX];        // x[t][m], stride 9
    __shared__ float ob[TT*SX];        // out[t][m]
    __shared__ float Z1[MROW*SZ];
    __shared__ float Z2[MROW*SZ];
    // h split hi/lo, A-operand order [m][k]; rows 8..15 stay zero (M padding)
    __shared__ __align__(16) short H1h[16*SH], H1l[16*SH], H2h[16*SH], H2l[16*SH];

    const int tid = threadIdx.x;
    const int w = tid >> 6, lane = tid & 63, quad = lane >> 4, n16 = lane & 15;
    const int row0 = blockIdx.x * MROW;

    // stage input (coalesced global, conflict-free LDS via odd stride)
    for (int i = 0; i < MROW; ++i) {
        int idx = i * BT + tid; int m = idx >> 9, t = idx & 511;
        xs[t * SX + m] = input[(row0 + m) * TT + t];
    }
    // zero H splits (incl. pad rows) and Z buffers (incl. never-written cols)
    for (int i = tid; i < 16 * SH / 2; i += BT) {
        ((int*)H1h)[i] = 0; ((int*)H1l)[i] = 0; ((int*)H2h)[i] = 0; ((int*)H2l)[i] = 0;
    }
    for (int i = tid; i < MROW * SZ; i += BT) { Z1[i] = 0.f; Z2[i] = 0.f; }

    // ---- persistent weight B-fragments: wave w owns N-tiles [tb, tb+ntile)
    const int ntile = (w < 5) ? 2 : 1;
    const int tb    = (w < 5) ? (2 * w) : (5 + w);   // 0,2,4,6,8,10,11,12
    // B-frag layout: lane(n16,quad) holds B[k=quad*8+j][n16] = W[jg][k]
    bf16x8 Bh[3][2][2], Bl[3][2][2];   // [matrix: hh1,ih2,hh2][slot][ktile]
    float bbt1[2], bbt2[2], wih[2];
    const float* Wm[3] = { W_hh1, W_ih2, W_hh2 };
#pragma unroll
    for (int i = 0; i < 2; ++i) {
        int jg = (tb + i) * 16 + n16;
        bool v = (i < ntile) && (jg < 4 * Hh);
        bbt1[i] = v ? (b_ih1[jg] + b_hh1[jg]) : 0.f;
        bbt2[i] = v ? (b_ih2[jg] + b_hh2[jg]) : 0.f;
        wih[i]  = v ? W_ih1[jg] : 0.f;
#pragma unroll
        for (int mt = 0; mt < 3; ++mt) {
#pragma unroll
            for (int kt = 0; kt < 2; ++kt) {
#pragma unroll
                for (int jj = 0; jj < 8; ++jj) {
                    int k = kt * 32 + quad * 8 + jj;
                    float val = (v && k < Hh) ? Wm[mt][jg * Hh + k] : 0.f;
                    float hf = topf(val);
                    Bh[mt][i][kt][jj] = topb(val);
                    Bl[mt][i][kt][jj] = topb(val - hf);
                }
            }
        }
    }
    const float wlin = (lane < Hh) ? W_lin[lane] : 0.f;
    const float blin = b_lin[0];
    float c1 = 0.f, c2 = 0.f;          // thread (w,lane): row w, hidden index lane

    __syncthreads();

    for (int t = 0; t < TT; ++t) {
        // ---- P1: z1 = Whh1·h1_old  (3-term split GEMM), + bias + x·wih1
        bf16x8 a1h0 = *(const bf16x8*)&H1h[n16*SH + quad*8];
        bf16x8 a1h1 = *(const bf16x8*)&H1h[n16*SH + 32 + quad*8];
        bf16x8 a1l0 = *(const bf16x8*)&H1l[n16*SH + quad*8];
        bf16x8 a1l1 = *(const bf16x8*)&H1l[n16*SH + 32 + quad*8];
#pragma unroll
        for (int i = 0; i < 2; ++i) {
            if (i < ntile) {
                f32x4 acc = (f32x4){0.f,0.f,0.f,0.f};
                acc = MFMA(a1h0, Bh[0][i][0], acc);
                acc = MFMA(a1l0, Bh[0][i][0], acc);
                acc = MFMA(a1h0, Bl[0][i][0], acc);
                acc = MFMA(a1h1, Bh[0][i][1], acc);
                acc = MFMA(a1l1, Bh[0][i][1], acc);
                acc = MFMA(a1h1, Bl[0][i][1], acc);
                if (quad < 2) {                    // C rows m=quad*4+r; only m<8 valid
                    int jc = (tb + i) * 16 + n16;
#pragma unroll
                    for (int r = 0; r < 4; ++r) {
                        int m = quad * 4 + r;
                        Z1[m * SZ + jc] = acc[r] + bbt1[i] + xs[t * SX + m] * wih[i];
                    }
                }
            }
        }
        __syncthreads();                                       // A

        // ---- P2: az2 = Whh2·h2_old (independent MFMA) + layer-1 gate update
        bf16x8 a2h0 = *(const bf16x8*)&H2h[n16*SH + quad*8];
        bf16x8 a2h1 = *(const bf16x8*)&H2h[n16*SH + 32 + quad*8];
        bf16x8 a2l0 = *(const bf16x8*)&H2l[n16*SH + quad*8];
        bf16x8 a2l1 = *(const bf16x8*)&H2l[n16*SH + 32 + quad*8];
        f32x4 az2[2];
#pragma unroll
        for (int i = 0; i < 2; ++i) {
            az2[i] = (f32x4){0.f,0.f,0.f,0.f};
            if (i < ntile) {
                az2[i] = MFMA(a2h0, Bh[2][i][0], az2[i]);
                az2[i] = MFMA(a2l0, Bh[2][i][0], az2[i]);
                az2[i] = MFMA(a2h0, Bl[2][i][0], az2[i]);
                az2[i] = MFMA(a2h1, Bh[2][i][1], az2[i]);
                az2[i] = MFMA(a2l1, Bh[2][i][1], az2[i]);
                az2[i] = MFMA(a2h1, Bl[2][i][1], az2[i]);
            }
        }
        {
            float zi = Z1[w * SZ + lane];
            float zf = Z1[w * SZ + lane + Hh];
            float zg = Z1[w * SZ + lane + 2 * Hh];
            float zo = Z1[w * SZ + lane + 3 * Hh];
            float ii = sigm(zi), ff = sigm(zf), gg = ftanh(zg), oo = sigm(zo);
            c1 = fmaf(ff, c1, ii * gg);
            float h1 = oo * ftanh(c1);
            if (lane < Hh) {
                float hf = topf(h1);
                H1h[w * SH + lane] = topb(h1);
                H1l[w * SH + lane] = topb(h1 - hf);
            }
        }
        __syncthreads();                                       // B

        // ---- P3: az2 += Wih2·h1_new ; write z2
        bf16x8 b1h0 = *(const bf16x8*)&H1h[n16*SH + quad*8];
        bf16x8 b1h1 = *(const bf16x8*)&H1h[n16*SH + 32 + quad*8];
        bf16x8 b1l0 = *(const bf16x8*)&H1l[n16*SH + quad*8];
        bf16x8 b1l1 = *(const bf16x8*)&H1l[n16*SH + 32 + quad*8];
#pragma unroll
        for (int i = 0; i < 2; ++i) {
            if (i < ntile) {
                az2[i] = MFMA(b1h0, Bh[1][i][0], az2[i]);
                az2[i] = MFMA(b1l0, Bh[1][i][0], az2[i]);
                az2[i] = MFMA(b1h0, Bl[1][i][0], az2[i]);
                az2[i] = MFMA(b1h1, Bh[1][i][1], az2[i]);
                az2[i] = MFMA(b1l1, Bh[1][i][1], az2[i]);
                az2[i] = MFMA(b1h1, Bl[1][i][1], az2[i]);
                if (quad < 2) {
                    int jc = (tb + i) * 16 + n16;
#pragma unroll
                    for (int r = 0; r < 4; ++r)
                        Z2[(quad * 4 + r) * SZ + jc] = az2[i][r] + bbt2[i];
                }
            }
        }
        __syncthreads();                                       // C

        // ---- P4: layer-2 gate update + output dot product
        {
            float zi = Z2[w * SZ + lane];
            float zf = Z2[w * SZ + lane + Hh];
            float zg = Z2[w * SZ + lane + 2 * Hh];
            float zo = Z2[w * SZ + lane + 3 * Hh];
            float ii = sigm(zi), ff = sigm(zf), gg = ftanh(zg), oo = sigm(zo);
            c2 = fmaf(ff, c2, ii * gg);
            float h2 = oo * ftanh(c2);
            if (lane < Hh) {
                float hf = topf(h2);
                H2h[w * SH + lane] = topb(h2);
                H2l[w * SH + lane] = topb(h2 - hf);
            }
            float p = (lane < Hh) ? wlin * h2 : 0.f;   // guard: lanes>=51 hold garbage
#pragma unroll
            for (int off = 32; off >= 1; off >>= 1)
                p += __shfl_xor(p, off, 64);
            if (lane == 0) ob[t * SX + w] = p + blin;
        }
        __syncthreads();                                       // D
    }

    // flush outputs (coalesced in t)
    for (int i = 0; i < MROW; ++i) {
        int idx = i * BT + tid; int m = idx >> 9, t = idx & 511;
        out[(row0 + m) * TT + t] = ob[t * SX + m];
    }
}

extern "C" void kernel_launch(void* const* d_in, const int* in_sizes, int n_in,
                              void* d_out, int out_size, void* d_ws, size_t ws_size,
                              hipStream_t stream) {
    const float* input = (const float*)d_in[0];
    const float* W_ih1 = (const float*)d_in[1];
    const float* W_hh1 = (const float*)d_in[2];
    const float* b_ih1 = (const float*)d_in[3];
    const float* b_hh1 = (const float*)d_in[4];
    const float* W_ih2 = (const float*)d_in[5];
    const float* W_hh2 = (const float*)d_in[6];
    const float* b_ih2 = (const float*)d_in[7];
    const float* b_hh2 = (const float*)d_in[8];
    const float* W_lin = (const float*)d_in[9];
    const float* b_lin = (const float*)d_in[10];
    float* out = (float*)d_out;

    hipLaunchKernelGGL(lstm2_mfma, dim3(NBLK), dim3(BT), 0, stream,
                       input, W_ih1, W_hh1, b_ih1, b_hh1,
                       W_ih2, W_hh2, b_ih2, b_hh2, W_lin, b_lin, out);
}

// Round 5
// 873.932 us; speedup vs baseline: 1.0312x; 1.0312x over previous
//
#include <hip/hip_runtime.h>

#define Hh 51
#define G4 204
#define TT 512
#define MROW 4
#define NBLK 128     // 512 / MROW
#define BT 256       // 4 waves
#define SH 80        // H row stride in shorts (160B): conflict-minimal + 16B aligned
#define SZR 209      // Z row stride in floats (row-major [m][j])
#define SX 5         // xs/ob stride
#define LOG2E 1.4426950408889634f

typedef __attribute__((ext_vector_type(8))) short bf16x8;
typedef __attribute__((ext_vector_type(4))) float f32x4;

__device__ __forceinline__ float fexp2(float x){ return __builtin_amdgcn_exp2f(x); }
__device__ __forceinline__ float frcp(float x){ return __builtin_amdgcn_rcpf(x); }
__device__ __forceinline__ float sigm(float x){ return frcp(1.f + fexp2(-LOG2E*x)); }
__device__ __forceinline__ float ftanh(float x){ return 1.f - 2.f*frcp(1.f + fexp2(2.f*LOG2E*x)); }
__device__ __forceinline__ short topb(float v){ return (short)(__float_as_uint(v)>>16); }
__device__ __forceinline__ float topf(float v){ return __uint_as_float(__float_as_uint(v)&0xFFFF0000u); }

#define MFMA(a,b,c) __builtin_amdgcn_mfma_f32_16x16x32_bf16(a,b,c,0,0,0)

__global__ __launch_bounds__(BT, 1) void lstm2_mfma4(
    const float* __restrict__ input,   // [512,512]
    const float* __restrict__ W_ih1,   // [204]
    const float* __restrict__ W_hh1,   // [204,51]
    const float* __restrict__ b_ih1,
    const float* __restrict__ b_hh1,
    const float* __restrict__ W_ih2,   // [204,51]
    const float* __restrict__ W_hh2,   // [204,51]
    const float* __restrict__ b_ih2,
    const float* __restrict__ b_hh2,
    const float* __restrict__ W_lin,   // [51]
    const float* __restrict__ b_lin,   // [1]
    float* __restrict__ out)           // [512,512]
{
    __shared__ float xs[TT*SX];                 // x[t][m]
    __shared__ float ob[TT*SX];                 // out[t][m]
    __shared__ float Zr1[MROW*SZR];             // z row-major [m][j]
    __shared__ float Zr2[MROW*SZR];
    __shared__ __align__(16) short H1h[16*SH], H1l[16*SH], H2h[16*SH], H2l[16*SH];

    const int tid  = threadIdx.x;
    const int w    = tid >> 6;         // wave 0..3; owns batch row w and N-slots
    const int lane = tid & 63;
    const int quad = lane >> 4;
    const int n16  = lane & 15;
    const int row0 = blockIdx.x * MROW;

    // stage inputs (coalesced in t)
    for (int i = 0; i < 8; ++i) {
        int idx = i * BT + tid; int m = idx >> 9, t = idx & 511;
        xs[t * SX + m] = input[(row0 + m) * TT + t];
    }
    // zero H arrays (pad rows m>=4 and k in [51,64) must stay 0)
    for (int i = tid; i < 16 * SH / 2; i += BT) {
        ((int*)H1h)[i] = 0; ((int*)H1l)[i] = 0;
        ((int*)H2h)[i] = 0; ((int*)H2l)[i] = 0;
    }

    // ---- persistent weight B-fragments: wave w owns N-slots [3w, 3w+ns)
    const int ns = (w == 3) ? 4 : 3;
    const int s0 = 3 * w;
    // B-frag: lane(n16,quad) holds B[k=kt*32+quad*8+jj][n=n16] = W[jg][k]
    bf16x8 Bh[3][4][2], Bl[3][4][2];   // [mat: hh1,ih2,hh2][slot][ktile]
    float bbt1[4], bbt2[4], wih[4];
    const float* Wm[3] = { W_hh1, W_ih2, W_hh2 };
#pragma unroll
    for (int i = 0; i < 4; ++i) {
        int jg = (s0 + i) * 16 + n16;
        bool v = (i < ns) && (jg < G4);
        bbt1[i] = v ? (b_ih1[jg] + b_hh1[jg]) : 0.f;
        bbt2[i] = v ? (b_ih2[jg] + b_hh2[jg]) : 0.f;
        wih[i]  = v ? W_ih1[jg] : 0.f;
#pragma unroll
        for (int mt = 0; mt < 3; ++mt) {
#pragma unroll
            for (int kt = 0; kt < 2; ++kt) {
#pragma unroll
                for (int jj = 0; jj < 8; ++jj) {
                    int k = kt * 32 + quad * 8 + jj;
                    float val = (v && k < Hh) ? Wm[mt][jg * Hh + k] : 0.f;
                    float hf = topf(val);
                    Bh[mt][i][kt][jj] = topb(val);
                    Bl[mt][i][kt][jj] = topb(val - hf);
                }
            }
        }
    }
    const float wlin = (lane < Hh) ? W_lin[lane] : 0.f;
    const float blin = b_lin[0];
    float c1 = 0.f, c2 = 0.f;          // wave w, lane l<51: state of row w, index l

    // h1 A-fragments carried in registers across iterations (h1 only changes in P2)
    bf16x8 A1h0 = {0,0,0,0,0,0,0,0}, A1h1 = {0,0,0,0,0,0,0,0};
    bf16x8 A1l0 = {0,0,0,0,0,0,0,0}, A1l1 = {0,0,0,0,0,0,0,0};

    __syncthreads();

    for (int t = 0; t < TT; ++t) {
        // ---- P1: Z1 = Whh1·h1_old + bias + x*wih1   (A-frags reused from P3/init)
        float x0 = xs[t*SX+0], x1 = xs[t*SX+1], x2 = xs[t*SX+2], x3 = xs[t*SX+3];
#pragma unroll
        for (int i = 0; i < 4; ++i) {
            if (i < ns) {
                f32x4 acc = (f32x4){0.f,0.f,0.f,0.f};
                acc = MFMA(A1h0, Bh[0][i][0], acc);
                acc = MFMA(A1h1, Bh[0][i][1], acc);
                acc = MFMA(A1l0, Bh[0][i][0], acc);
                acc = MFMA(A1l1, Bh[0][i][1], acc);
                acc = MFMA(A1h0, Bl[0][i][0], acc);
                acc = MFMA(A1h1, Bl[0][i][1], acc);
                if (quad == 0) {       // C rows m=quad*4+r; valid m<4
                    int jc = (s0 + i) * 16 + n16;
                    Zr1[0*SZR + jc] = acc[0] + bbt1[i] + x0 * wih[i];
                    Zr1[1*SZR + jc] = acc[1] + bbt1[i] + x1 * wih[i];
                    Zr1[2*SZR + jc] = acc[2] + bbt1[i] + x2 * wih[i];
                    Zr1[3*SZR + jc] = acc[3] + bbt1[i] + x3 * wih[i];
                }
            }
        }
        __syncthreads();                                   // A: Z1 ready

        // ---- P2: az = Whh2·h2_old (MFMA) + layer-1 gate update (VALU) overlap
        bf16x8 A2h0 = *(const bf16x8*)&H2h[n16*SH + quad*8];
        bf16x8 A2h1 = *(const bf16x8*)&H2h[n16*SH + 32 + quad*8];
        bf16x8 A2l0 = *(const bf16x8*)&H2l[n16*SH + quad*8];
        bf16x8 A2l1 = *(const bf16x8*)&H2l[n16*SH + 32 + quad*8];
        f32x4 az[4];
#pragma unroll
        for (int i = 0; i < 4; ++i) {
            az[i] = (f32x4){0.f,0.f,0.f,0.f};
            if (i < ns) {
                az[i] = MFMA(A2h0, Bh[2][i][0], az[i]);
                az[i] = MFMA(A2h1, Bh[2][i][1], az[i]);
                az[i] = MFMA(A2l0, Bh[2][i][0], az[i]);
                az[i] = MFMA(A2l1, Bh[2][i][1], az[i]);
                az[i] = MFMA(A2h0, Bl[2][i][0], az[i]);
                az[i] = MFMA(A2h1, Bl[2][i][1], az[i]);
            }
        }
        if (lane < Hh) {               // gate 1 for row w
            float zi = Zr1[w*SZR + lane];
            float zf = Zr1[w*SZR + lane + Hh];
            float zg = Zr1[w*SZR + lane + 2*Hh];
            float zo = Zr1[w*SZR + lane + 3*Hh];
            float ii = sigm(zi), ff = sigm(zf), gg = ftanh(zg), oo = sigm(zo);
            c1 = fmaf(ff, c1, ii * gg);
            float h1 = oo * ftanh(c1);
            float hf = topf(h1);
            H1h[w*SH + lane] = topb(h1);
            H1l[w*SH + lane] = topb(h1 - hf);
        }
        __syncthreads();                                   // B: H1 fragments ready

        // ---- P3: az += Wih2·h1_new ; Z2 = az + bias   (refresh A1 frags for next P1)
        A1h0 = *(const bf16x8*)&H1h[n16*SH + quad*8];
        A1h1 = *(const bf16x8*)&H1h[n16*SH + 32 + quad*8];
        A1l0 = *(const bf16x8*)&H1l[n16*SH + quad*8];
        A1l1 = *(const bf16x8*)&H1l[n16*SH + 32 + quad*8];
#pragma unroll
        for (int i = 0; i < 4; ++i) {
            if (i < ns) {
                az[i] = MFMA(A1h0, Bh[1][i][0], az[i]);
                az[i] = MFMA(A1h1, Bh[1][i][1], az[i]);
                az[i] = MFMA(A1l0, Bh[1][i][0], az[i]);
                az[i] = MFMA(A1l1, Bh[1][i][1], az[i]);
                az[i] = MFMA(A1h0, Bl[1][i][0], az[i]);
                az[i] = MFMA(A1h1, Bl[1][i][1], az[i]);
                if (quad == 0) {
                    int jc = (s0 + i) * 16 + n16;
                    Zr2[0*SZR + jc] = az[i][0] + bbt2[i];
                    Zr2[1*SZR + jc] = az[i][1] + bbt2[i];
                    Zr2[2*SZR + jc] = az[i][2] + bbt2[i];
                    Zr2[3*SZR + jc] = az[i][3] + bbt2[i];
                }
            }
        }
        __syncthreads();                                   // C: Z2 ready

        // ---- P4: layer-2 gate update + output reduce (no barrier; A fences next use)
        float p = 0.f;
        if (lane < Hh) {
            float zi = Zr2[w*SZR + lane];
            float zf = Zr2[w*SZR + lane + Hh];
            float zg = Zr2[w*SZR + lane + 2*Hh];
            float zo = Zr2[w*SZR + lane + 3*Hh];
            float ii = sigm(zi), ff = sigm(zf), gg = ftanh(zg), oo = sigm(zo);
            c2 = fmaf(ff, c2, ii * gg);
            float h2 = oo * ftanh(c2);
            float hf = topf(h2);
            H2h[w*SH + lane] = topb(h2);
            H2l[w*SH + lane] = topb(h2 - hf);
            p = wlin * h2;
        }
#pragma unroll
        for (int off = 32; off >= 1; off >>= 1)
            p += __shfl_xor(p, off, 64);
        if (lane == 0) ob[t*SX + w] = p + blin;
    }

    __syncthreads();
    // flush outputs (coalesced in t)
    for (int i = 0; i < 8; ++i) {
        int idx = i * BT + tid; int m = idx >> 9, t = idx & 511;
        out[(row0 + m) * TT + t] = ob[t * SX + m];
    }
}

extern "C" void kernel_launch(void* const* d_in, const int* in_sizes, int n_in,
                              void* d_out, int out_size, void* d_ws, size_t ws_size,
                              hipStream_t stream) {
    const float* input = (const float*)d_in[0];
    const float* W_ih1 = (const float*)d_in[1];
    const float* W_hh1 = (const float*)d_in[2];
    const float* b_ih1 = (const float*)d_in[3];
    const float* b_hh1 = (const float*)d_in[4];
    const float* W_ih2 = (const float*)d_in[5];
    const float* W_hh2 = (const float*)d_in[6];
    const float* b_ih2 = (const float*)d_in[7];
    const float* b_hh2 = (const float*)d_in[8];
    const float* W_lin = (const float*)d_in[9];
    const float* b_lin = (const float*)d_in[10];
    float* out = (float*)d_out;

    hipLaunchKernelGGL(lstm2_mfma4, dim3(NBLK), dim3(BT), 0, stream,
                       input, W_ih1, W_hh1, b_ih1, b_hh1,
                       W_ih2, W_hh2, b_ih2, b_hh2, W_lin, b_lin, out);
}

// Round 6
// 771.474 us; speedup vs baseline: 1.1682x; 1.1328x over previous
//
#include <hip/hip_runtime.h>

#define Hh 51
#define G4 204
#define TT 512
#define MR 4            // batch rows per block
#define NBLK 128        // 512 / MR
#define BT 512          // 8 waves: 0-3 layer-1, 4-7 layer-2
#define SHR 80          // H row stride in shorts (160B) - proven conflict-free b128 reads (R5)
#define NIT 514         // 512 steps + 2 pipeline-drain iterations
#define LOG2E 1.4426950408889634f

typedef __attribute__((ext_vector_type(8))) short bf16x8;
typedef __attribute__((ext_vector_type(4))) float f32x4;

__device__ __forceinline__ float fexp2(float x){ return __builtin_amdgcn_exp2f(x); }
__device__ __forceinline__ float frcp(float x){ return __builtin_amdgcn_rcpf(x); }
__device__ __forceinline__ float sigm(float x){ return frcp(1.f + fexp2(-LOG2E*x)); }
__device__ __forceinline__ float ftanh(float x){ return 1.f - 2.f*frcp(1.f + fexp2(2.f*LOG2E*x)); }
__device__ __forceinline__ short topb(float v){ return (short)(__float_as_uint(v)>>16); }
__device__ __forceinline__ float topf(float v){ return __uint_as_float(__float_as_uint(v)&0xFFFF0000u); }

#define MFMA(a,b,c) __builtin_amdgcn_mfma_f32_16x16x32_bf16(a,b,c,0,0,0)

__global__ __launch_bounds__(BT, 2) void lstm2_pipe(
    const float* __restrict__ input,   // [512,512]
    const float* __restrict__ W_ih1,   // [204]
    const float* __restrict__ W_hh1,   // [204,51]
    const float* __restrict__ b_ih1,
    const float* __restrict__ b_hh1,
    const float* __restrict__ W_ih2,   // [204,51]
    const float* __restrict__ W_hh2,   // [204,51]
    const float* __restrict__ b_ih2,
    const float* __restrict__ b_hh2,
    const float* __restrict__ W_lin,   // [51]
    const float* __restrict__ b_lin,   // [1]
    float* __restrict__ out)           // [512,512]
{
    __shared__ float xs[TT*MR];        // x[t][m]
    __shared__ float ob[TT*MR];        // out[t][m]
    // h state, A-frag layout [m][k] bf16 hi/lo, double-buffered by parity
    __shared__ __align__(16) short H1h[2][16*SHR], H1l[2][16*SHR];
    __shared__ __align__(16) short H2h[2][16*SHR], H2l[2][16*SHR];

    const int tid  = threadIdx.x;
    const int wv   = tid >> 6;
    const int lane = tid & 63;
    const int quad = lane >> 4;
    const int n16  = lane & 15;
    const int row0 = blockIdx.x * MR;
    const bool g1  = (wv < 4);
    const int  w   = g1 ? wv : (wv - 4);       // wave index within group
    const int  l   = 13 * w + n16;             // hidden unit owned by this lane-column
    const bool valid = (n16 <= 12) && (l < Hh);

    // ---- stage input rows (coalesced in t)
#pragma unroll
    for (int i = 0; i < MR; ++i) {
        int idx = i * BT + tid; int m = idx >> 9, t = idx & 511;
        xs[t * MR + m] = input[(row0 + m) * TT + t];
    }
    // ---- zero h buffers (both parities; pad rows m>=4 and k in [51,64) stay 0)
    for (int i = tid; i < 2 * 16 * SHR / 2; i += BT) {
        ((int*)H1h)[i] = 0; ((int*)H1l)[i] = 0;
        ((int*)H2h)[i] = 0; ((int*)H2l)[i] = 0;
    }

    // ---- persistent weight B-fragments, gate-interleaved permutation:
    // tile g (g=0..3 = gate i,f,g,o), col c=n16  <->  weight row g*51 + (13w+c)
    bf16x8 z8 = {0,0,0,0,0,0,0,0};
    bf16x8 B1h[4][2], B1l[4][2];   // W_hh1  (group 1)
    bf16x8 B2h[4][2], B2l[4][2];   // W_ih2  (group 2)
    bf16x8 B3h[4][2], B3l[4][2];   // W_hh2  (group 2)
    bf16x8 Bouth[2], Boutl[2];     // W_lin column (wave 7)
    float bb[4], wih[4];
#pragma unroll
    for (int gt = 0; gt < 4; ++gt) {
        int jrow = gt * Hh + l;
        bb[gt]  = valid ? (g1 ? (b_ih1[jrow] + b_hh1[jrow]) : (b_ih2[jrow] + b_hh2[jrow])) : 0.f;
        wih[gt] = (valid && g1) ? W_ih1[jrow] : 0.f;
#pragma unroll
        for (int kt = 0; kt < 2; ++kt) {
            B1h[gt][kt] = z8; B1l[gt][kt] = z8;
            B2h[gt][kt] = z8; B2l[gt][kt] = z8;
            B3h[gt][kt] = z8; B3l[gt][kt] = z8;
#pragma unroll
            for (int jj = 0; jj < 8; ++jj) {
                int k = kt * 32 + quad * 8 + jj;
                if (valid && k < Hh) {
                    if (g1) {
                        float v = W_hh1[jrow * Hh + k];
                        B1h[gt][kt][jj] = topb(v); B1l[gt][kt][jj] = topb(v - topf(v));
                    } else {
                        float v2 = W_ih2[jrow * Hh + k];
                        B2h[gt][kt][jj] = topb(v2); B2l[gt][kt][jj] = topb(v2 - topf(v2));
                        float v3 = W_hh2[jrow * Hh + k];
                        B3h[gt][kt][jj] = topb(v3); B3l[gt][kt][jj] = topb(v3 - topf(v3));
                    }
                }
            }
        }
    }
#pragma unroll
    for (int kt = 0; kt < 2; ++kt) {
        Bouth[kt] = z8; Boutl[kt] = z8;
#pragma unroll
        for (int jj = 0; jj < 8; ++jj) {
            int k = kt * 32 + quad * 8 + jj;
            if (wv == 7 && n16 == 0 && k < Hh) {
                float v = W_lin[k];
                Bouth[kt][jj] = topb(v); Boutl[kt][jj] = topb(v - topf(v));
            }
        }
    }
    const float blin = b_lin[0];
    float cst = 0.f;   // c1 (group-1 lanes) or c2 (group-2 lanes) for state (m=quad, l)

    __syncthreads();

    for (int n = 0; n < NIT; ++n) {
        const int pA = (n + 1) & 1;    // parity of (n-1): h1(n-1) read, h2(n-1) write
        const int pB = n & 1;          // parity of n: h1(n) write; (n-2): h2(n-2) read

        if (g1) {
            if (n < TT) {
                // ---- layer-1, time n: z1 = Whh1·h1(n-1) + x(n)·wih1 + b1
                bf16x8 ah0 = *(const bf16x8*)&H1h[pA][n16*SHR + quad*8];
                bf16x8 ah1 = *(const bf16x8*)&H1h[pA][n16*SHR + 32 + quad*8];
                bf16x8 al0 = *(const bf16x8*)&H1l[pA][n16*SHR + quad*8];
                bf16x8 al1 = *(const bf16x8*)&H1l[pA][n16*SHR + 32 + quad*8];
                f32x4 ac[4];
#pragma unroll
                for (int gt = 0; gt < 4; ++gt) {
                    f32x4 a = (f32x4){0.f,0.f,0.f,0.f};
                    a = MFMA(ah0, B1h[gt][0], a);
                    a = MFMA(ah1, B1h[gt][1], a);
                    a = MFMA(al0, B1h[gt][0], a);
                    a = MFMA(al1, B1h[gt][1], a);
                    a = MFMA(ah0, B1l[gt][0], a);
                    a = MFMA(ah1, B1l[gt][1], a);
                    ac[gt] = a;
                }
                // spread rows to quads: lane (c,q) takes row m=q of column l
                float x = xs[n * MR + quad];
                float z[4];
#pragma unroll
                for (int gt = 0; gt < 4; ++gt) {
                    float s1 = __shfl_xor(ac[gt][1], 16);
                    float s2 = __shfl_xor(ac[gt][2], 32);
                    float s3 = __shfl_xor(ac[gt][3], 48);
                    float zg = (quad == 0) ? ac[gt][0] : (quad == 1) ? s1 : (quad == 2) ? s2 : s3;
                    z[gt] = zg + bb[gt] + x * wih[gt];
                }
                if (valid) {
                    float ii = sigm(z[0]), ff = sigm(z[1]), gg = ftanh(z[2]), oo = sigm(z[3]);
                    cst = fmaf(ff, cst, ii * gg);
                    float h = oo * ftanh(cst);
                    float hf = topf(h);
                    H1h[pB][quad*SHR + l] = topb(h);
                    H1l[pB][quad*SHR + l] = topb(h - hf);
                }
            }
        } else if (n >= 1) {
            // ---- layer-2, time n-1 (+ output for time n-2)
            bf16x8 a1h0 = *(const bf16x8*)&H1h[pA][n16*SHR + quad*8];
            bf16x8 a1h1 = *(const bf16x8*)&H1h[pA][n16*SHR + 32 + quad*8];
            bf16x8 a1l0 = *(const bf16x8*)&H1l[pA][n16*SHR + quad*8];
            bf16x8 a1l1 = *(const bf16x8*)&H1l[pA][n16*SHR + 32 + quad*8];
            bf16x8 a2h0 = *(const bf16x8*)&H2h[pB][n16*SHR + quad*8];
            bf16x8 a2h1 = *(const bf16x8*)&H2h[pB][n16*SHR + 32 + quad*8];
            bf16x8 a2l0 = *(const bf16x8*)&H2l[pB][n16*SHR + quad*8];
            bf16x8 a2l1 = *(const bf16x8*)&H2l[pB][n16*SHR + 32 + quad*8];
            if (n <= TT) {
                // z2 = Wih2·h1(n-1) + Whh2·h2(n-2) + b2
                f32x4 ac[4];
#pragma unroll
                for (int gt = 0; gt < 4; ++gt) {
                    f32x4 a = (f32x4){0.f,0.f,0.f,0.f};
                    a = MFMA(a2h0, B3h[gt][0], a);
                    a = MFMA(a2h1, B3h[gt][1], a);
                    a = MFMA(a2l0, B3h[gt][0], a);
                    a = MFMA(a2l1, B3h[gt][1], a);
                    a = MFMA(a2h0, B3l[gt][0], a);
                    a = MFMA(a2h1, B3l[gt][1], a);
                    a = MFMA(a1h0, B2h[gt][0], a);
                    a = MFMA(a1h1, B2h[gt][1], a);
                    a = MFMA(a1l0, B2h[gt][0], a);
                    a = MFMA(a1l1, B2h[gt][1], a);
                    a = MFMA(a1h0, B2l[gt][0], a);
                    a = MFMA(a1h1, B2l[gt][1], a);
                    ac[gt] = a;
                }
                float z[4];
#pragma unroll
                for (int gt = 0; gt < 4; ++gt) {
                    float s1 = __shfl_xor(ac[gt][1], 16);
                    float s2 = __shfl_xor(ac[gt][2], 32);
                    float s3 = __shfl_xor(ac[gt][3], 48);
                    float zg = (quad == 0) ? ac[gt][0] : (quad == 1) ? s1 : (quad == 2) ? s2 : s3;
                    z[gt] = zg + bb[gt];
                }
                if (valid) {
                    float ii = sigm(z[0]), ff = sigm(z[1]), gg = ftanh(z[2]), oo = sigm(z[3]);
                    cst = fmaf(ff, cst, ii * gg);
                    float h = oo * ftanh(cst);
                    float hf = topf(h);
                    H2h[pA][quad*SHR + l] = topb(h);
                    H2l[pA][quad*SHR + l] = topb(h - hf);
                }
            }
            if (wv == 7 && n >= 2) {
                // out(n-2) = wlin · h2(n-2) + blin  (h2(n-2) frags already loaded)
                f32x4 ao = (f32x4){0.f,0.f,0.f,0.f};
                ao = MFMA(a2h0, Bouth[0], ao);
                ao = MFMA(a2h1, Bouth[1], ao);
                ao = MFMA(a2l0, Bouth[0], ao);
                ao = MFMA(a2l1, Bouth[1], ao);
                ao = MFMA(a2h0, Boutl[0], ao);
                ao = MFMA(a2h1, Boutl[1], ao);
                if (lane == 0) {
                    float4 o;
                    o.x = ao[0] + blin; o.y = ao[1] + blin;
                    o.z = ao[2] + blin; o.w = ao[3] + blin;
                    *(float4*)&ob[(n - 2) * MR] = o;
                }
            }
        }
        __syncthreads();   // publishes h1(n) and h2(n-1) for iteration n+1
    }

    // ---- flush outputs (coalesced in t)
#pragma unroll
    for (int i = 0; i < MR; ++i) {
        int idx = i * BT + tid; int m = idx >> 9, t = idx & 511;
        out[(row0 + m) * TT + t] = ob[t * MR + m];
    }
}

extern "C" void kernel_launch(void* const* d_in, const int* in_sizes, int n_in,
                              void* d_out, int out_size, void* d_ws, size_t ws_size,
                              hipStream_t stream) {
    const float* input = (const float*)d_in[0];
    const float* W_ih1 = (const float*)d_in[1];
    const float* W_hh1 = (const float*)d_in[2];
    const float* b_ih1 = (const float*)d_in[3];
    const float* b_hh1 = (const float*)d_in[4];
    const float* W_ih2 = (const float*)d_in[5];
    const float* W_hh2 = (const float*)d_in[6];
    const float* b_ih2 = (const float*)d_in[7];
    const float* b_hh2 = (const float*)d_in[8];
    const float* W_lin = (const float*)d_in[9];
    const float* b_lin = (const float*)d_in[10];
    float* out = (float*)d_out;

    hipLaunchKernelGGL(lstm2_pipe, dim3(NBLK), dim3(BT), 0, stream,
                       input, W_ih1, W_hh1, b_ih1, b_hh1,
                       W_ih2, W_hh2, b_ih2, b_hh2, W_lin, b_lin, out);
}

// Round 8
// 671.834 us; speedup vs baseline: 1.3415x; 1.1483x over previous
//
#include <hip/hip_runtime.h>

#define Hh 51
#define TT 512
#define MR 2            // batch rows per block
#define NBLK 256        // 512 / MR -> one block per CU, all 256 CUs
#define BT 512          // 8 waves: 0-3 layer-1, 4-7 layer-2
#define SHR 80          // H row stride in shorts (160B), conflict-free b128 reads (R5/R6)
#define NIT 514         // 512 steps + 2 pipeline-drain iterations
#define LOG2E 1.4426950408889634f

typedef __attribute__((ext_vector_type(8))) short bf16x8;
typedef __attribute__((ext_vector_type(4))) float f32x4;

__device__ __forceinline__ float fexp2(float x){ return __builtin_amdgcn_exp2f(x); }
__device__ __forceinline__ float frcp(float x){ return __builtin_amdgcn_rcpf(x); }
__device__ __forceinline__ float sigm(float x){ return frcp(1.f + fexp2(-LOG2E*x)); }
__device__ __forceinline__ float ftanh(float x){ return 1.f - 2.f*frcp(1.f + fexp2(2.f*LOG2E*x)); }
__device__ __forceinline__ short topb(float v){ return (short)(__float_as_uint(v)>>16); }
__device__ __forceinline__ float topf(float v){ return __uint_as_float(__float_as_uint(v)&0xFFFF0000u); }

#define MFMA(a,b,c) __builtin_amdgcn_mfma_f32_16x16x32_bf16(a,b,c,0,0,0)

__global__ __launch_bounds__(BT, 2) void lstm2_pipe2(
    const float* __restrict__ input,   // [512,512]
    const float* __restrict__ W_ih1,   // [204]
    const float* __restrict__ W_hh1,   // [204,51]
    const float* __restrict__ b_ih1,
    const float* __restrict__ b_hh1,
    const float* __restrict__ W_ih2,   // [204,51]
    const float* __restrict__ W_hh2,   // [204,51]
    const float* __restrict__ b_ih2,
    const float* __restrict__ b_hh2,
    const float* __restrict__ W_lin,   // [51]
    const float* __restrict__ b_lin,   // [1]
    float* __restrict__ out)           // [512,512]
{
    __shared__ float xs[TT*MR];        // x[t][m]
    __shared__ float ob[TT*MR];        // out[t][m]
    // h state, A-frag layout [m][k] bf16 hi/lo, double-buffered by parity.
    // Rows m=0,1 live; rows 2-15 stay zero (M padding for the 16x16 tile).
    __shared__ __align__(16) short H1h[2][16*SHR], H1l[2][16*SHR];
    __shared__ __align__(16) short H2h[2][16*SHR], H2l[2][16*SHR];

    const int tid  = threadIdx.x;
    const int wv   = tid >> 6;
    const int lane = tid & 63;
    const int quad = lane >> 4;
    const int n16  = lane & 15;
    const int row0 = blockIdx.x * MR;
    const bool g1  = (wv < 4);
    const int  w   = g1 ? wv : (wv - 4);       // wave index within group
    const int  l   = 13 * w + n16;             // hidden unit owned by this lane-column
    const bool valid = (n16 <= 12) && (l < Hh);

    // ---- stage input rows (coalesced in t)
#pragma unroll
    for (int i = 0; i < MR; ++i) {
        int idx = i * BT + tid; int m = idx >> 9, t = idx & 511;
        xs[t * MR + m] = input[(row0 + m) * TT + t];
    }
    // ---- zero h buffers (both parities; pad rows and k in [51,64) stay 0)
    for (int i = tid; i < 2 * 16 * SHR / 2; i += BT) {
        ((int*)H1h)[i] = 0; ((int*)H1l)[i] = 0;
        ((int*)H2h)[i] = 0; ((int*)H2l)[i] = 0;
    }

    // ---- persistent weight B-fragments, gate-interleaved permutation:
    // tile gt (gate i,f,g,o), col c=n16  <->  weight row gt*51 + (13w+c)
    bf16x8 z8 = {0,0,0,0,0,0,0,0};
    bf16x8 B1h[4][2], B1l[4][2];   // W_hh1  (group 1)
    bf16x8 B2h[4][2], B2l[4][2];   // W_ih2  (group 2)
    bf16x8 B3h[4][2], B3l[4][2];   // W_hh2  (group 2)
    bf16x8 Bouth[2], Boutl[2];     // W_lin column (wave 7)
    float bb[4], wih[4];
#pragma unroll
    for (int gt = 0; gt < 4; ++gt) {
        int jrow = gt * Hh + l;
        bb[gt]  = valid ? (g1 ? (b_ih1[jrow] + b_hh1[jrow]) : (b_ih2[jrow] + b_hh2[jrow])) : 0.f;
        wih[gt] = (valid && g1) ? W_ih1[jrow] : 0.f;
#pragma unroll
        for (int kt = 0; kt < 2; ++kt) {
            B1h[gt][kt] = z8; B1l[gt][kt] = z8;
            B2h[gt][kt] = z8; B2l[gt][kt] = z8;
            B3h[gt][kt] = z8; B3l[gt][kt] = z8;
#pragma unroll
            for (int jj = 0; jj < 8; ++jj) {
                int k = kt * 32 + quad * 8 + jj;
                if (valid && k < Hh) {
                    if (g1) {
                        float v = W_hh1[jrow * Hh + k];
                        B1h[gt][kt][jj] = topb(v); B1l[gt][kt][jj] = topb(v - topf(v));
                    } else {
                        float v2 = W_ih2[jrow * Hh + k];
                        B2h[gt][kt][jj] = topb(v2); B2l[gt][kt][jj] = topb(v2 - topf(v2));
                        float v3 = W_hh2[jrow * Hh + k];
                        B3h[gt][kt][jj] = topb(v3); B3l[gt][kt][jj] = topb(v3 - topf(v3));
                    }
                }
            }
        }
    }
#pragma unroll
    for (int kt = 0; kt < 2; ++kt) {
        Bouth[kt] = z8; Boutl[kt] = z8;
#pragma unroll
        for (int jj = 0; jj < 8; ++jj) {
            int k = kt * 32 + quad * 8 + jj;
            if (wv == 7 && n16 == 0 && k < Hh) {
                float v = W_lin[k];
                Bouth[kt][jj] = topb(v); Boutl[kt][jj] = topb(v - topf(v));
            }
        }
    }
    const float blin = b_lin[0];
    float cst0 = 0.f, cst1 = 0.f;  // cell states for rows m=0,1 (quad0 lanes, unit l)

    __syncthreads();

    for (int n = 0; n < NIT; ++n) {
        const int pA = (n + 1) & 1;    // parity of (n-1): h1(n-1) read, h2(n-1) write
        const int pB = n & 1;          // parity of n: h1(n) write; (n-2): h2(n-2) read

        if (g1) {
            if (n < TT) {
                // ---- layer-1, time n: z1 = Whh1·h1(n-1) + x(n)·wih1 + b1
                bf16x8 ah0 = *(const bf16x8*)&H1h[pA][n16*SHR + quad*8];
                bf16x8 ah1 = *(const bf16x8*)&H1h[pA][n16*SHR + 32 + quad*8];
                bf16x8 al0 = *(const bf16x8*)&H1l[pA][n16*SHR + quad*8];
                bf16x8 al1 = *(const bf16x8*)&H1l[pA][n16*SHR + 32 + quad*8];
                f32x4 ac[4];
#pragma unroll
                for (int gt = 0; gt < 4; ++gt) {
                    f32x4 a = (f32x4){0.f,0.f,0.f,0.f};
                    a = MFMA(ah0, B1h[gt][0], a);
                    a = MFMA(ah1, B1h[gt][1], a);
                    a = MFMA(al0, B1h[gt][0], a);
                    a = MFMA(al1, B1h[gt][1], a);
                    a = MFMA(ah0, B1l[gt][0], a);
                    a = MFMA(ah1, B1l[gt][1], a);
                    ac[gt] = a;
                }
                // C-layout: lane(c, quad=0) regs 0,1 = rows m=0,1 at col c. In-lane update.
                if (quad == 0 && valid) {
                    float x0 = xs[n * MR + 0], x1 = xs[n * MR + 1];
                    {   // m = 0
                        float zi = ac[0][0] + bb[0] + x0 * wih[0];
                        float zf = ac[1][0] + bb[1] + x0 * wih[1];
                        float zg = ac[2][0] + bb[2] + x0 * wih[2];
                        float zo = ac[3][0] + bb[3] + x0 * wih[3];
                        float ii = sigm(zi), ff = sigm(zf), gg = ftanh(zg), oo = sigm(zo);
                        cst0 = fmaf(ff, cst0, ii * gg);
                        float h = oo * ftanh(cst0);
                        float hf = topf(h);
                        H1h[pB][l] = topb(h);
                        H1l[pB][l] = topb(h - hf);
                    }
                    {   // m = 1
                        float zi = ac[0][1] + bb[0] + x1 * wih[0];
                        float zf = ac[1][1] + bb[1] + x1 * wih[1];
                        float zg = ac[2][1] + bb[2] + x1 * wih[2];
                        float zo = ac[3][1] + bb[3] + x1 * wih[3];
                        float ii = sigm(zi), ff = sigm(zf), gg = ftanh(zg), oo = sigm(zo);
                        cst1 = fmaf(ff, cst1, ii * gg);
                        float h = oo * ftanh(cst1);
                        float hf = topf(h);
                        H1h[pB][SHR + l] = topb(h);
                        H1l[pB][SHR + l] = topb(h - hf);
                    }
                }
            }
        } else if (n >= 1) {
            // ---- layer-2, time n-1 (+ output for time n-2)
            bf16x8 a1h0 = *(const bf16x8*)&H1h[pA][n16*SHR + quad*8];
            bf16x8 a1h1 = *(const bf16x8*)&H1h[pA][n16*SHR + 32 + quad*8];
            bf16x8 a1l0 = *(const bf16x8*)&H1l[pA][n16*SHR + quad*8];
            bf16x8 a1l1 = *(const bf16x8*)&H1l[pA][n16*SHR + 32 + quad*8];
            bf16x8 a2h0 = *(const bf16x8*)&H2h[pB][n16*SHR + quad*8];
            bf16x8 a2h1 = *(const bf16x8*)&H2h[pB][n16*SHR + 32 + quad*8];
            bf16x8 a2l0 = *(const bf16x8*)&H2l[pB][n16*SHR + quad*8];
            bf16x8 a2l1 = *(const bf16x8*)&H2l[pB][n16*SHR + 32 + quad*8];
            if (n <= TT) {
                // z2 = Wih2·h1(n-1) + Whh2·h2(n-2) + b2
                f32x4 ac[4];
#pragma unroll
                for (int gt = 0; gt < 4; ++gt) {
                    f32x4 a = (f32x4){0.f,0.f,0.f,0.f};
                    a = MFMA(a2h0, B3h[gt][0], a);
                    a = MFMA(a2h1, B3h[gt][1], a);
                    a = MFMA(a2l0, B3h[gt][0], a);
                    a = MFMA(a2l1, B3h[gt][1], a);
                    a = MFMA(a2h0, B3l[gt][0], a);
                    a = MFMA(a2h1, B3l[gt][1], a);
                    a = MFMA(a1h0, B2h[gt][0], a);
                    a = MFMA(a1h1, B2h[gt][1], a);
                    a = MFMA(a1l0, B2h[gt][0], a);
                    a = MFMA(a1l1, B2h[gt][1], a);
                    a = MFMA(a1h0, B2l[gt][0], a);
                    a = MFMA(a1h1, B2l[gt][1], a);
                    ac[gt] = a;
                }
                if (quad == 0 && valid) {
                    {   // m = 0
                        float zi = ac[0][0] + bb[0];
                        float zf = ac[1][0] + bb[1];
                        float zg = ac[2][0] + bb[2];
                        float zo = ac[3][0] + bb[3];
                        float ii = sigm(zi), ff = sigm(zf), gg = ftanh(zg), oo = sigm(zo);
                        cst0 = fmaf(ff, cst0, ii * gg);
                        float h = oo * ftanh(cst0);
                        float hf = topf(h);
                        H2h[pA][l] = topb(h);
                        H2l[pA][l] = topb(h - hf);
                    }
                    {   // m = 1
                        float zi = ac[0][1] + bb[0];
                        float zf = ac[1][1] + bb[1];
                        float zg = ac[2][1] + bb[2];
                        float zo = ac[3][1] + bb[3];
                        float ii = sigm(zi), ff = sigm(zf), gg = ftanh(zg), oo = sigm(zo);
                        cst1 = fmaf(ff, cst1, ii * gg);
                        float h = oo * ftanh(cst1);
                        float hf = topf(h);
                        H2h[pA][SHR + l] = topb(h);
                        H2l[pA][SHR + l] = topb(h - hf);
                    }
                }
            }
            if (wv == 7 && n >= 2) {
                // out(n-2) rows 0,1 = wlin · h2(n-2) + blin (h2(n-2) frags already loaded)
                f32x4 ao = (f32x4){0.f,0.f,0.f,0.f};
                ao = MFMA(a2h0, Bouth[0], ao);
                ao = MFMA(a2h1, Bouth[1], ao);
                ao = MFMA(a2l0, Bouth[0], ao);
                ao = MFMA(a2l1, Bouth[1], ao);
                ao = MFMA(a2h0, Boutl[0], ao);
                ao = MFMA(a2h1, Boutl[1], ao);
                if (lane == 0) {
                    ob[(n - 2) * MR + 0] = ao[0] + blin;
                    ob[(n - 2) * MR + 1] = ao[1] + blin;
                }
            }
        }
        __syncthreads();   // publishes h1(n) and h2(n-1) for iteration n+1
    }

    // ---- flush outputs (coalesced in t)
#pragma unroll
    for (int i = 0; i < MR; ++i) {
        int idx = i * BT + tid; int m = idx >> 9, t = idx & 511;
        out[(row0 + m) * TT + t] = ob[t * MR + m];
    }
}

extern "C" void kernel_launch(void* const* d_in, const int* in_sizes, int n_in,
                              void* d_out, int out_size, void* d_ws, size_t ws_size,
                              hipStream_t stream) {
    const float* input = (const float*)d_in[0];
    const float* W_ih1 = (const float*)d_in[1];
    const float* W_hh1 = (const float*)d_in[2];
    const float* b_ih1 = (const float*)d_in[3];
    const float* b_hh1 = (const float*)d_in[4];
    const float* W_ih2 = (const float*)d_in[5];
    const float* W_hh2 = (const float*)d_in[6];
    const float* b_ih2 = (const float*)d_in[7];
    const float* b_hh2 = (const float*)d_in[8];
    const float* W_lin = (const float*)d_in[9];
    const float* b_lin = (const float*)d_in[10];
    float* out = (float*)d_out;

    hipLaunchKernelGGL(lstm2_pipe2, dim3(NBLK), dim3(BT), 0, stream,
                       input, W_ih1, W_hh1, b_ih1, b_hh1,
                       W_ih2, W_hh2, b_ih2, b_hh2, W_lin, b_lin, out);
}

// Round 9
// 519.070 us; speedup vs baseline: 1.7362x; 1.2943x over previous
//
#include <hip/hip_runtime.h>

#define Hh 51
#define TT 512
#define MR 2            // batch rows per block (A-rows 0 and 4)
#define NBLK 256        // 512 / MR -> one block per CU, all 256 CUs
#define BT 512          // 8 waves: 0-3 layer-1, 4-7 layer-2
#define SHR 80          // H row stride in shorts (160B)
#define NIT 514         // 512 steps + 2 pipeline-drain iterations
#define LOG2E 1.4426950408889634f

typedef __attribute__((ext_vector_type(8))) short bf16x8;
typedef __attribute__((ext_vector_type(4))) float f32x4;

__device__ __forceinline__ float fexp2(float x){ return __builtin_amdgcn_exp2f(x); }
__device__ __forceinline__ float frcp(float x){ return __builtin_amdgcn_rcpf(x); }
__device__ __forceinline__ float sigm(float x){ return frcp(1.f + fexp2(-LOG2E*x)); }
__device__ __forceinline__ float ftanh(float x){ return 1.f - 2.f*frcp(1.f + fexp2(2.f*LOG2E*x)); }
__device__ __forceinline__ short topb(float v){ return (short)(__float_as_uint(v)>>16); }
__device__ __forceinline__ float topf(float v){ return __uint_as_float(__float_as_uint(v)&0xFFFF0000u); }

#define MFMA(a,b,c) __builtin_amdgcn_mfma_f32_16x16x32_bf16(a,b,c,0,0,0)

__global__ __launch_bounds__(BT, 2) void lstm2_mask(
    const float* __restrict__ input,   // [512,512]
    const float* __restrict__ W_ih1,   // [204]
    const float* __restrict__ W_hh1,   // [204,51]
    const float* __restrict__ b_ih1,
    const float* __restrict__ b_hh1,
    const float* __restrict__ W_ih2,   // [204,51]
    const float* __restrict__ W_hh2,   // [204,51]
    const float* __restrict__ b_ih2,
    const float* __restrict__ b_hh2,
    const float* __restrict__ W_lin,   // [51]
    const float* __restrict__ b_lin,   // [1]
    float* __restrict__ out)           // [512,512]
{
    __shared__ float xs[TT*MR];        // x[t][m]
    __shared__ float ob[TT*MR];        // out[t][m]
    // h state, A-frag layout [m][k] bf16 hi/lo, double-buffered by parity.
    // Live A-rows: 0 (batch row 0) and 4 (batch row 1); all other rows stay zero.
    __shared__ __align__(16) short H1h[2][16*SHR], H1l[2][16*SHR];
    __shared__ __align__(16) short H2h[2][16*SHR], H2l[2][16*SHR];

    const int tid  = threadIdx.x;
    const int wv   = tid >> 6;
    const int lane = tid & 63;
    const int quad = lane >> 4;
    const int n16  = lane & 15;
    const int row0 = blockIdx.x * MR;
    const bool g1  = (wv < 4);
    const int  w   = g1 ? wv : (wv - 4);       // wave index within group
    const int  l   = 13 * w + n16;             // hidden unit owned by this lane-column
    const bool valid = (n16 <= 12) && (l < Hh);
    const bool liveA = ((n16 & 11) == 0);      // n16 in {0,4}: the two live A-rows

    // ---- stage input rows (coalesced in t)
#pragma unroll
    for (int i = 0; i < MR; ++i) {
        int idx = i * BT + tid; int m = idx >> 9, t = idx & 511;
        xs[t * MR + m] = input[(row0 + m) * TT + t];
    }
    // ---- zero h buffers (both parities; all rows, incl. k in [51,64))
    for (int i = tid; i < 2 * 16 * SHR / 2; i += BT) {
        ((int*)H1h)[i] = 0; ((int*)H1l)[i] = 0;
        ((int*)H2h)[i] = 0; ((int*)H2l)[i] = 0;
    }

    // ---- persistent weight B-fragments, gate-interleaved permutation:
    // tile gt (gate i,f,g,o), col c=n16  <->  weight row gt*51 + (13w+c)
    bf16x8 z8 = {0,0,0,0,0,0,0,0};
    bf16x8 B1h[4][2], B1l[4][2];   // W_hh1  (group 1)
    bf16x8 B2h[4][2], B2l[4][2];   // W_ih2  (group 2)
    bf16x8 B3h[4][2], B3l[4][2];   // W_hh2  (group 2)
    bf16x8 Bouth[2], Boutl[2];     // W_lin column (wave 7)
    float bb[4], wih[4];
#pragma unroll
    for (int gt = 0; gt < 4; ++gt) {
        int jrow = gt * Hh + l;
        bb[gt]  = valid ? (g1 ? (b_ih1[jrow] + b_hh1[jrow]) : (b_ih2[jrow] + b_hh2[jrow])) : 0.f;
        wih[gt] = (valid && g1) ? W_ih1[jrow] : 0.f;
#pragma unroll
        for (int kt = 0; kt < 2; ++kt) {
            B1h[gt][kt] = z8; B1l[gt][kt] = z8;
            B2h[gt][kt] = z8; B2l[gt][kt] = z8;
            B3h[gt][kt] = z8; B3l[gt][kt] = z8;
#pragma unroll
            for (int jj = 0; jj < 8; ++jj) {
                int k = kt * 32 + quad * 8 + jj;
                if (valid && k < Hh) {
                    if (g1) {
                        float v = W_hh1[jrow * Hh + k];
                        B1h[gt][kt][jj] = topb(v); B1l[gt][kt][jj] = topb(v - topf(v));
                    } else {
                        float v2 = W_ih2[jrow * Hh + k];
                        B2h[gt][kt][jj] = topb(v2); B2l[gt][kt][jj] = topb(v2 - topf(v2));
                        float v3 = W_hh2[jrow * Hh + k];
                        B3h[gt][kt][jj] = topb(v3); B3l[gt][kt][jj] = topb(v3 - topf(v3));
                    }
                }
            }
        }
    }
#pragma unroll
    for (int kt = 0; kt < 2; ++kt) {
        Bouth[kt] = z8; Boutl[kt] = z8;
#pragma unroll
        for (int jj = 0; jj < 8; ++jj) {
            int k = kt * 32 + quad * 8 + jj;
            if (wv == 7 && n16 == 0 && k < Hh) {
                float v = W_lin[k];
                Bouth[kt][jj] = topb(v); Boutl[kt][jj] = topb(v - topf(v));
            }
        }
    }
    const float blin = b_lin[0];
    float cst = 0.f;   // cell state: quad0 lanes -> batch row 0, quad1 -> row 1 (unit l)

    // A-fragment registers persist across iterations; masked-out lanes keep zero.
    bf16x8 f1h0 = z8, f1h1 = z8, f1l0 = z8, f1l1 = z8;   // h1 frags (g1 and g2 use)
    bf16x8 f2h0 = z8, f2h1 = z8, f2l0 = z8, f2l1 = z8;   // h2 frags (g2 only)

    __syncthreads();

    for (int n = 0; n < NIT; ++n) {
        const int pA = (n + 1) & 1;    // parity of (n-1): h1(n-1) read, h2(n-1) write
        const int pB = n & 1;          // parity of n: h1(n) write; (n-2): h2(n-2) read

        if (g1) {
            if (n < TT) {
                // ---- layer-1, time n: z1 = Whh1·h1(n-1) + x(n)·wih1 + b1
                if (liveA) {           // only live A-rows move LDS data
                    const short* bh = &H1h[pA][n16*SHR + quad*8];
                    const short* bl = &H1l[pA][n16*SHR + quad*8];
                    f1h0 = *(const bf16x8*)(bh);
                    f1h1 = *(const bf16x8*)(bh + 32);
                    f1l0 = *(const bf16x8*)(bl);
                    f1l1 = *(const bf16x8*)(bl + 32);
                }
                f32x4 ac[4];
#pragma unroll
                for (int gt = 0; gt < 4; ++gt) {
                    f32x4 a = (f32x4){0.f,0.f,0.f,0.f};
                    a = MFMA(f1h0, B1h[gt][0], a);
                    a = MFMA(f1h1, B1h[gt][1], a);
                    a = MFMA(f1l0, B1h[gt][0], a);
                    a = MFMA(f1l1, B1h[gt][1], a);
                    a = MFMA(f1h0, B1l[gt][0], a);
                    a = MFMA(f1h1, B1l[gt][1], a);
                    ac[gt] = a;
                }
                // C-layout: row = quad*4 + reg -> row 0 = (q0,r0), row 4 = (q1,r0).
                if (quad < MR && valid) {
                    float x = xs[n * MR + quad];
                    float zi = ac[0][0] + bb[0] + x * wih[0];
                    float zf = ac[1][0] + bb[1] + x * wih[1];
                    float zg = ac[2][0] + bb[2] + x * wih[2];
                    float zo = ac[3][0] + bb[3] + x * wih[3];
                    float ii = sigm(zi), ff = sigm(zf), gg = ftanh(zg), oo = sigm(zo);
                    cst = fmaf(ff, cst, ii * gg);
                    float h = oo * ftanh(cst);
                    float hf = topf(h);
                    H1h[pB][(quad*4)*SHR + l] = topb(h);
                    H1l[pB][(quad*4)*SHR + l] = topb(h - hf);
                }
            }
        } else if (n >= 1) {
            // ---- layer-2, time n-1 (+ output for time n-2)
            if (liveA) {
                const short* b1h = &H1h[pA][n16*SHR + quad*8];
                const short* b1l = &H1l[pA][n16*SHR + quad*8];
                f1h0 = *(const bf16x8*)(b1h);
                f1h1 = *(const bf16x8*)(b1h + 32);
                f1l0 = *(const bf16x8*)(b1l);
                f1l1 = *(const bf16x8*)(b1l + 32);
                const short* b2h = &H2h[pB][n16*SHR + quad*8];
                const short* b2l = &H2l[pB][n16*SHR + quad*8];
                f2h0 = *(const bf16x8*)(b2h);
                f2h1 = *(const bf16x8*)(b2h + 32);
                f2l0 = *(const bf16x8*)(b2l);
                f2l1 = *(const bf16x8*)(b2l + 32);
            }
            if (n <= TT) {
                // z2 = Wih2·h1(n-1) + Whh2·h2(n-2) + b2
                f32x4 ac[4];
#pragma unroll
                for (int gt = 0; gt < 4; ++gt) {
                    f32x4 a = (f32x4){0.f,0.f,0.f,0.f};
                    a = MFMA(f2h0, B3h[gt][0], a);
                    a = MFMA(f2h1, B3h[gt][1], a);
                    a = MFMA(f2l0, B3h[gt][0], a);
                    a = MFMA(f2l1, B3h[gt][1], a);
                    a = MFMA(f2h0, B3l[gt][0], a);
                    a = MFMA(f2h1, B3l[gt][1], a);
                    a = MFMA(f1h0, B2h[gt][0], a);
                    a = MFMA(f1h1, B2h[gt][1], a);
                    a = MFMA(f1l0, B2h[gt][0], a);
                    a = MFMA(f1l1, B2h[gt][1], a);
                    a = MFMA(f1h0, B2l[gt][0], a);
                    a = MFMA(f1h1, B2l[gt][1], a);
                    ac[gt] = a;
                }
                if (quad < MR && valid) {
                    float zi = ac[0][0] + bb[0];
                    float zf = ac[1][0] + bb[1];
                    float zg = ac[2][0] + bb[2];
                    float zo = ac[3][0] + bb[3];
                    float ii = sigm(zi), ff = sigm(zf), gg = ftanh(zg), oo = sigm(zo);
                    cst = fmaf(ff, cst, ii * gg);
                    float h = oo * ftanh(cst);
                    float hf = topf(h);
                    H2h[pA][(quad*4)*SHR + l] = topb(h);
                    H2l[pA][(quad*4)*SHR + l] = topb(h - hf);
                }
            }
            if (wv == 7 && n >= 2) {
                // out(n-2) = wlin · h2(n-2) + blin  (h2(n-2) frags already loaded)
                f32x4 ao = (f32x4){0.f,0.f,0.f,0.f};
                ao = MFMA(f2h0, Bouth[0], ao);
                ao = MFMA(f2h1, Bouth[1], ao);
                ao = MFMA(f2l0, Bouth[0], ao);
                ao = MFMA(f2l1, Bouth[1], ao);
                ao = MFMA(f2h0, Boutl[0], ao);
                ao = MFMA(f2h1, Boutl[1], ao);
                if (n16 == 0 && quad < MR)        // lanes 0,16: rows 0,4 -> batch rows 0,1
                    ob[(n - 2) * MR + quad] = ao[0] + blin;
            }
        }
        __syncthreads();   // publishes h1(n) and h2(n-1) for iteration n+1
    }

    // ---- flush outputs (coalesced in t)
#pragma unroll
    for (int i = 0; i < MR; ++i) {
        int idx = i * BT + tid; int m = idx >> 9, t = idx & 511;
        out[(row0 + m) * TT + t] = ob[t * MR + m];
    }
}

extern "C" void kernel_launch(void* const* d_in, const int* in_sizes, int n_in,
                              void* d_out, int out_size, void* d_ws, size_t ws_size,
                              hipStream_t stream) {
    const float* input = (const float*)d_in[0];
    const float* W_ih1 = (const float*)d_in[1];
    const float* W_hh1 = (const float*)d_in[2];
    const float* b_ih1 = (const float*)d_in[3];
    const float* b_hh1 = (const float*)d_in[4];
    const float* W_ih2 = (const float*)d_in[5];
    const float* W_hh2 = (const float*)d_in[6];
    const float* b_ih2 = (const float*)d_in[7];
    const float* b_hh2 = (const float*)d_in[8];
    const float* W_lin = (const float*)d_in[9];
    const float* b_lin = (const float*)d_in[10];
    float* out = (float*)d_out;

    hipLaunchKernelGGL(lstm2_mask, dim3(NBLK), dim3(BT), 0, stream,
                       input, W_ih1, W_hh1, b_ih1, b_hh1,
                       W_ih2, W_hh2, b_ih2, b_hh2, W_lin, b_lin, out);
}

// Round 10
// 307.711 us; speedup vs baseline: 2.9288x; 1.6869x over previous
//
#include <hip/hip_runtime.h>

#define Hh 51
#define TT 512
#define MR 2            // batch rows per block (A-rows 0 and 4)
#define NBLK 256        // 512 / MR -> one block per CU, all 256 CUs
#define BT 512          // 8 waves: 0-3 layer-1, 4-7 layer-2
#define SHR 80          // H row stride in fp16 elems (160B)
#define NIT 514         // 512 steps + 2 pipeline-drain iterations
#define LOG2E 1.4426950408889634f

typedef _Float16 half8 __attribute__((ext_vector_type(8)));
typedef __attribute__((ext_vector_type(4))) float f32x4;

__device__ __forceinline__ float fexp2(float x){ return __builtin_amdgcn_exp2f(x); }
__device__ __forceinline__ float frcp(float x){ return __builtin_amdgcn_rcpf(x); }
__device__ __forceinline__ float sigm(float x){ return frcp(1.f + fexp2(-LOG2E*x)); }
__device__ __forceinline__ float ftanh(float x){ return 1.f - 2.f*frcp(1.f + fexp2(2.f*LOG2E*x)); }

#define MFMAH(a,b,c) __builtin_amdgcn_mfma_f32_16x16x32_f16(a,b,c,0,0,0)

__global__ __launch_bounds__(BT, 2) void lstm2_fp16(
    const float* __restrict__ input,   // [512,512]
    const float* __restrict__ W_ih1,   // [204]
    const float* __restrict__ W_hh1,   // [204,51]
    const float* __restrict__ b_ih1,
    const float* __restrict__ b_hh1,
    const float* __restrict__ W_ih2,   // [204,51]
    const float* __restrict__ W_hh2,   // [204,51]
    const float* __restrict__ b_ih2,
    const float* __restrict__ b_hh2,
    const float* __restrict__ W_lin,   // [51]
    const float* __restrict__ b_lin,   // [1]
    float* __restrict__ out)           // [512,512]
{
    __shared__ float xs[TT*MR];        // x[t][m]
    __shared__ float ob[TT*MR];        // out[t][m]
    // h state, A-frag layout [m][k] fp16, double-buffered by parity.
    // Live A-rows: 0 (batch row 0) and 4 (batch row 1); all other rows stay zero.
    __shared__ __align__(16) _Float16 H1[2][16*SHR];
    __shared__ __align__(16) _Float16 H2[2][16*SHR];

    const int tid  = threadIdx.x;
    const int wv   = tid >> 6;
    const int lane = tid & 63;
    const int quad = lane >> 4;
    const int n16  = lane & 15;
    const int row0 = blockIdx.x * MR;
    const bool g1  = (wv < 4);
    const int  w   = g1 ? wv : (wv - 4);       // wave index within group
    const int  l   = 13 * w + n16;             // hidden unit owned by this lane-column
    const bool valid = (n16 <= 12) && (l < Hh);
    const bool liveA = ((n16 & 11) == 0);      // n16 in {0,4}: the two live A-rows

    // ---- stage input rows (coalesced in t)
#pragma unroll
    for (int i = 0; i < MR; ++i) {
        int idx = i * BT + tid; int m = idx >> 9, t = idx & 511;
        xs[t * MR + m] = input[(row0 + m) * TT + t];
    }
    // ---- zero h buffers (both parities; all rows, incl. k in [51,64))
    for (int i = tid; i < 2 * 16 * SHR / 2; i += BT) {
        ((int*)H1)[i] = 0; ((int*)H2)[i] = 0;
    }

    // ---- persistent weight B-fragments (fp16), gate-interleaved permutation:
    // tile gt (gate i,f,g,o), col c=n16  <->  weight row gt*51 + (13w+c)
    half8 z8 = {0,0,0,0,0,0,0,0};
    half8 B1[4][2];                // W_hh1  (group 1)
    half8 B2[4][2], B3[4][2];      // W_ih2, W_hh2 (group 2)
    half8 Bout[2];                 // W_lin column (wave 7)
    float bb[4], wih[4];
#pragma unroll
    for (int gt = 0; gt < 4; ++gt) {
        int jrow = gt * Hh + l;
        bb[gt]  = valid ? (g1 ? (b_ih1[jrow] + b_hh1[jrow]) : (b_ih2[jrow] + b_hh2[jrow])) : 0.f;
        wih[gt] = (valid && g1) ? W_ih1[jrow] : 0.f;
#pragma unroll
        for (int kt = 0; kt < 2; ++kt) {
            B1[gt][kt] = z8; B2[gt][kt] = z8; B3[gt][kt] = z8;
#pragma unroll
            for (int jj = 0; jj < 8; ++jj) {
                int k = kt * 32 + quad * 8 + jj;
                if (valid && k < Hh) {
                    if (g1) {
                        B1[gt][kt][jj] = (_Float16)W_hh1[jrow * Hh + k];
                    } else {
                        B2[gt][kt][jj] = (_Float16)W_ih2[jrow * Hh + k];
                        B3[gt][kt][jj] = (_Float16)W_hh2[jrow * Hh + k];
                    }
                }
            }
        }
    }
#pragma unroll
    for (int kt = 0; kt < 2; ++kt) {
        Bout[kt] = z8;
#pragma unroll
        for (int jj = 0; jj < 8; ++jj) {
            int k = kt * 32 + quad * 8 + jj;
            if (wv == 7 && n16 == 0 && k < Hh)
                Bout[kt][jj] = (_Float16)W_lin[k];
        }
    }
    const float blin = b_lin[0];
    float cst = 0.f;   // cell state: quad0 lanes -> batch row 0, quad1 -> row 1 (unit l)

    // A-fragment registers persist across iterations; masked-out lanes keep zero.
    half8 f1a = z8, f1b = z8;      // h1 frags (g1 and g2 use)
    half8 f2a = z8, f2b = z8;      // h2 frags (g2 only)

    __syncthreads();

    for (int n = 0; n < NIT; ++n) {
        const int pA = (n + 1) & 1;    // parity of (n-1): h1(n-1) read, h2(n-1) write
        const int pB = n & 1;          // parity of n: h1(n) write; (n-2): h2(n-2) read

        if (g1) {
            if (n < TT) {
                // ---- layer-1, time n: z1 = Whh1·h1(n-1) + x(n)·wih1 + b1
                if (liveA) {           // only live A-rows move LDS data
                    const _Float16* bp = &H1[pA][n16*SHR + quad*8];
                    f1a = *(const half8*)(bp);
                    f1b = *(const half8*)(bp + 32);
                }
                f32x4 ac[4];
#pragma unroll
                for (int gt = 0; gt < 4; ++gt) {
                    f32x4 a = (f32x4){0.f,0.f,0.f,0.f};
                    a = MFMAH(f1a, B1[gt][0], a);
                    a = MFMAH(f1b, B1[gt][1], a);
                    ac[gt] = a;
                }
                // C-layout: row = quad*4 + reg -> row 0 = (q0,r0), row 4 = (q1,r0).
                if (quad < MR && valid) {
                    float x = xs[n * MR + quad];
                    float zi = ac[0][0] + bb[0] + x * wih[0];
                    float zf = ac[1][0] + bb[1] + x * wih[1];
                    float zg = ac[2][0] + bb[2] + x * wih[2];
                    float zo = ac[3][0] + bb[3] + x * wih[3];
                    float ii = sigm(zi), ff = sigm(zf), gg = ftanh(zg), oo = sigm(zo);
                    cst = fmaf(ff, cst, ii * gg);
                    float h = oo * ftanh(cst);
                    H1[pB][(quad*4)*SHR + l] = (_Float16)h;
                }
            }
        } else if (n >= 1) {
            // ---- layer-2, time n-1 (+ output for time n-2)
            if (liveA) {
                f1a = *(const half8*)&H1[pA][n16*SHR + quad*8];
                f1b = *(const half8*)&H1[pA][n16*SHR + quad*8 + 32];
                f2a = *(const half8*)&H2[pB][n16*SHR + quad*8];
                f2b = *(const half8*)&H2[pB][n16*SHR + quad*8 + 32];
            }
            if (n <= TT) {
                // z2 = Wih2·h1(n-1) + Whh2·h2(n-2) + b2
                f32x4 ac[4];
#pragma unroll
                for (int gt = 0; gt < 4; ++gt) {
                    f32x4 a = (f32x4){0.f,0.f,0.f,0.f};
                    a = MFMAH(f2a, B3[gt][0], a);
                    a = MFMAH(f2b, B3[gt][1], a);
                    a = MFMAH(f1a, B2[gt][0], a);
                    a = MFMAH(f1b, B2[gt][1], a);
                    ac[gt] = a;
                }
                if (quad < MR && valid) {
                    float zi = ac[0][0] + bb[0];
                    float zf = ac[1][0] + bb[1];
                    float zg = ac[2][0] + bb[2];
                    float zo = ac[3][0] + bb[3];
                    float ii = sigm(zi), ff = sigm(zf), gg = ftanh(zg), oo = sigm(zo);
                    cst = fmaf(ff, cst, ii * gg);
                    float h = oo * ftanh(cst);
                    H2[pA][(quad*4)*SHR + l] = (_Float16)h;
                }
            }
            if (wv == 7 && n >= 2) {
                // out(n-2) = wlin · h2(n-2) + blin  (h2(n-2) frags already loaded)
                f32x4 ao = (f32x4){0.f,0.f,0.f,0.f};
                ao = MFMAH(f2a, Bout[0], ao);
                ao = MFMAH(f2b, Bout[1], ao);
                if (n16 == 0 && quad < MR)        // lanes 0,16: rows 0,4 -> batch rows 0,1
                    ob[(n - 2) * MR + quad] = ao[0] + blin;
            }
        }
        __syncthreads();   // publishes h1(n) and h2(n-1) for iteration n+1
    }

    // ---- flush outputs (coalesced in t)
#pragma unroll
    for (int i = 0; i < MR; ++i) {
        int idx = i * BT + tid; int m = idx >> 9, t = idx & 511;
        out[(row0 + m) * TT + t] = ob[t * MR + m];
    }
}

extern "C" void kernel_launch(void* const* d_in, const int* in_sizes, int n_in,
                              void* d_out, int out_size, void* d_ws, size_t ws_size,
                              hipStream_t stream) {
    const float* input = (const float*)d_in[0];
    const float* W_ih1 = (const float*)d_in[1];
    const float* W_hh1 = (const float*)d_in[2];
    const float* b_ih1 = (const float*)d_in[3];
    const float* b_hh1 = (const float*)d_in[4];
    const float* W_ih2 = (const float*)d_in[5];
    const float* W_hh2 = (const float*)d_in[6];
    const float* b_ih2 = (const float*)d_in[7];
    const float* b_hh2 = (const float*)d_in[8];
    const float* W_lin = (const float*)d_in[9];
    const float* b_lin = (const float*)d_in[10];
    float* out = (float*)d_out;

    hipLaunchKernelGGL(lstm2_fp16, dim3(NBLK), dim3(BT), 0, stream,
                       input, W_ih1, W_hh1, b_ih1, b_hh1,
                       W_ih2, W_hh2, b_ih2, b_hh2, W_lin, b_lin, out);
}

// Round 11
// 292.889 us; speedup vs baseline: 3.0770x; 1.0506x over previous
//
#include <hip/hip_runtime.h>

#define Hh 51
#define TT 512
#define MR 2            // batch rows per block (A-rows 0 and 4)
#define NBLK 256        // 512 / MR -> one block per CU, all 256 CUs
#define BT 512          // 8 waves: 0-3 layer-1, 4-7 layer-2
#define SHR 80          // H row stride in fp16 elems (160B)
#define NIT 514         // 512 steps + 2 pipeline-drain iterations (even)
#define LOG2E 1.4426950408889634f

typedef _Float16 half8 __attribute__((ext_vector_type(8)));
typedef __attribute__((ext_vector_type(4))) float f32x4;

__device__ __forceinline__ float fexp2(float x){ return __builtin_amdgcn_exp2f(x); }
__device__ __forceinline__ float frcp(float x){ return __builtin_amdgcn_rcpf(x); }
__device__ __forceinline__ float sigm(float x){ return frcp(1.f + fexp2(-LOG2E*x)); }
__device__ __forceinline__ float ftanh(float x){ return 1.f - 2.f*frcp(1.f + fexp2(2.f*LOG2E*x)); }

#define MFMAH(a,b,c) __builtin_amdgcn_mfma_f32_16x16x32_f16(a,b,c,0,0,0)

__global__ __launch_bounds__(BT, 2) void lstm2_fp16u(
    const float* __restrict__ input,   // [512,512]
    const float* __restrict__ W_ih1,   // [204]
    const float* __restrict__ W_hh1,   // [204,51]
    const float* __restrict__ b_ih1,
    const float* __restrict__ b_hh1,
    const float* __restrict__ W_ih2,   // [204,51]
    const float* __restrict__ W_hh2,   // [204,51]
    const float* __restrict__ b_ih2,
    const float* __restrict__ b_hh2,
    const float* __restrict__ W_lin,   // [51]
    const float* __restrict__ b_lin,   // [1]
    float* __restrict__ out)           // [512,512]
{
    __shared__ float xs[TT*MR];        // x[t][m]
    __shared__ float ob[TT*MR];        // out[t][m]
    // h state, A-frag layout [m][k] fp16, double-buffered by parity.
    // Live A-rows: 0 (batch row 0) and 4 (batch row 1); all other rows stay zero.
    __shared__ __align__(16) _Float16 H1[2][16*SHR];
    __shared__ __align__(16) _Float16 H2[2][16*SHR];

    const int tid  = threadIdx.x;
    const int wv   = tid >> 6;
    const int lane = tid & 63;
    const int quad = lane >> 4;
    const int n16  = lane & 15;
    const int row0 = blockIdx.x * MR;
    const bool g1  = (wv < 4);
    const int  w   = g1 ? wv : (wv - 4);       // wave index within group
    const int  l   = 13 * w + n16;             // hidden unit owned by this lane-column
    const bool valid = (n16 <= 12) && (l < Hh);
    const bool liveA = ((n16 & 11) == 0);      // n16 in {0,4}: the two live A-rows
    const bool updL  = (quad < MR) && valid;   // lanes doing the gate/state update
    const int  fo    = n16 * SHR + quad * 8;   // A-frag element offset (loop-invariant)
    const int  ho    = (quad * 4) * SHR + l;   // h store offset (rows 0 / 4)

    // ---- stage input rows (coalesced in t)
#pragma unroll
    for (int i = 0; i < MR; ++i) {
        int idx = i * BT + tid; int m = idx >> 9, t = idx & 511;
        xs[t * MR + m] = input[(row0 + m) * TT + t];
    }
    // ---- zero h buffers (both parities; all rows, incl. k in [51,64))
    for (int i = tid; i < 2 * 16 * SHR / 2; i += BT) {
        ((int*)H1)[i] = 0; ((int*)H2)[i] = 0;
    }

    // ---- persistent weight B-fragments (fp16), gate-interleaved permutation:
    // tile gt (gate i,f,g,o), col c=n16  <->  weight row gt*51 + (13w+c)
    half8 z8 = {0,0,0,0,0,0,0,0};
    half8 B1[4][2];                // W_hh1  (group 1)
    half8 B2[4][2], B3[4][2];      // W_ih2, W_hh2 (group 2)
    half8 Bout[2];                 // W_lin column (wave 7)
    float bb[4], wih[4];
#pragma unroll
    for (int gt = 0; gt < 4; ++gt) {
        int jrow = gt * Hh + l;
        bb[gt]  = valid ? (g1 ? (b_ih1[jrow] + b_hh1[jrow]) : (b_ih2[jrow] + b_hh2[jrow])) : 0.f;
        wih[gt] = (valid && g1) ? W_ih1[jrow] : 0.f;
#pragma unroll
        for (int kt = 0; kt < 2; ++kt) {
            B1[gt][kt] = z8; B2[gt][kt] = z8; B3[gt][kt] = z8;
#pragma unroll
            for (int jj = 0; jj < 8; ++jj) {
                int k = kt * 32 + quad * 8 + jj;
                if (valid && k < Hh) {
                    if (g1) {
                        B1[gt][kt][jj] = (_Float16)W_hh1[jrow * Hh + k];
                    } else {
                        B2[gt][kt][jj] = (_Float16)W_ih2[jrow * Hh + k];
                        B3[gt][kt][jj] = (_Float16)W_hh2[jrow * Hh + k];
                    }
                }
            }
        }
    }
#pragma unroll
    for (int kt = 0; kt < 2; ++kt) {
        Bout[kt] = z8;
#pragma unroll
        for (int jj = 0; jj < 8; ++jj) {
            int k = kt * 32 + quad * 8 + jj;
            if (wv == 7 && n16 == 0 && k < Hh)
                Bout[kt][jj] = (_Float16)W_lin[k];
        }
    }
    const float blin = b_lin[0];
    float cst = 0.f;   // cell state: quad0 lanes -> batch row 0, quad1 -> row 1 (unit l)

    // A-fragment registers persist across iterations; masked-out lanes keep zero.
    half8 f1a = z8, f1b = z8;      // h1 frags (g1 and g2 use)
    half8 f2a = z8, f2b = z8;      // h2 frags (g2 only)

    __syncthreads();

    // one pipeline step; pA/pB are always compile-time literals at call sites
    auto stepfn = [&](int n, int pA, int pB) {
        if (g1) {
            if (n < TT) {
                // ---- layer-1, time n: z1 = Whh1·h1(n-1) + x(n)·wih1 + b1
                float x = xs[n * MR + quad];       // issue early; used after MFMAs
                if (liveA) {                       // only live A-rows move LDS data
                    const _Float16* bp = &H1[pA][fo];
                    f1a = *(const half8*)(bp);
                    f1b = *(const half8*)(bp + 32);
                }
                f32x4 ac[4];
#pragma unroll
                for (int gt = 0; gt < 4; ++gt) {
                    f32x4 a = (f32x4){0.f,0.f,0.f,0.f};
                    a = MFMAH(f1a, B1[gt][0], a);
                    a = MFMAH(f1b, B1[gt][1], a);
                    ac[gt] = a;
                }
                // C-layout: row = quad*4 + reg -> row 0 = (q0,r0), row 4 = (q1,r0).
                if (updL) {
                    float zi = ac[0][0] + bb[0] + x * wih[0];
                    float zf = ac[1][0] + bb[1] + x * wih[1];
                    float zg = ac[2][0] + bb[2] + x * wih[2];
                    float zo = ac[3][0] + bb[3] + x * wih[3];
                    float ii = sigm(zi), ff = sigm(zf), gg = ftanh(zg), oo = sigm(zo);
                    cst = fmaf(ff, cst, ii * gg);
                    float h = oo * ftanh(cst);
                    H1[pB][ho] = (_Float16)h;
                }
            }
        } else if (n >= 1) {
            // ---- layer-2, time n-1 (+ output for time n-2)
            if (liveA) {
                f1a = *(const half8*)&H1[pA][fo];
                f1b = *(const half8*)&H1[pA][fo + 32];
                f2a = *(const half8*)&H2[pB][fo];
                f2b = *(const half8*)&H2[pB][fo + 32];
            }
            if (n <= TT) {
                // z2 = Wih2·h1(n-1) + Whh2·h2(n-2) + b2
                f32x4 ac[4];
#pragma unroll
                for (int gt = 0; gt < 4; ++gt) {
                    f32x4 a = (f32x4){0.f,0.f,0.f,0.f};
                    a = MFMAH(f2a, B3[gt][0], a);
                    a = MFMAH(f2b, B3[gt][1], a);
                    a = MFMAH(f1a, B2[gt][0], a);
                    a = MFMAH(f1b, B2[gt][1], a);
                    ac[gt] = a;
                }
                if (updL) {
                    float zi = ac[0][0] + bb[0];
                    float zf = ac[1][0] + bb[1];
                    float zg = ac[2][0] + bb[2];
                    float zo = ac[3][0] + bb[3];
                    float ii = sigm(zi), ff = sigm(zf), gg = ftanh(zg), oo = sigm(zo);
                    cst = fmaf(ff, cst, ii * gg);
                    float h = oo * ftanh(cst);
                    H2[pA][ho] = (_Float16)h;
                }
            }
            if (wv == 7 && n >= 2) {
                // out(n-2) = wlin · h2(n-2) + blin  (h2(n-2) frags already loaded)
                f32x4 ao = (f32x4){0.f,0.f,0.f,0.f};
                ao = MFMAH(f2a, Bout[0], ao);
                ao = MFMAH(f2b, Bout[1], ao);
                if (n16 == 0 && quad < MR)        // lanes 0,16: rows 0,4 -> batch rows 0,1
                    ob[(n - 2) * MR + quad] = ao[0] + blin;
            }
        }
        __syncthreads();   // publishes h1(n) and h2(n-1) for iteration n+1
    };

    // unroll x2: parity literals fold all LDS addressing to base+constant
    for (int k2 = 0; k2 < NIT / 2; ++k2) {
        stepfn(2 * k2,     1, 0);
        stepfn(2 * k2 + 1, 0, 1);
    }

    // ---- flush outputs (coalesced in t)
#pragma unroll
    for (int i = 0; i < MR; ++i) {
        int idx = i * BT + tid; int m = idx >> 9, t = idx & 511;
        out[(row0 + m) * TT + t] = ob[t * MR + m];
    }
}

extern "C" void kernel_launch(void* const* d_in, const int* in_sizes, int n_in,
                              void* d_out, int out_size, void* d_ws, size_t ws_size,
                              hipStream_t stream) {
    const float* input = (const float*)d_in[0];
    const float* W_ih1 = (const float*)d_in[1];
    const float* W_hh1 = (const float*)d_in[2];
    const float* b_ih1 = (const float*)d_in[3];
    const float* b_hh1 = (const float*)d_in[4];
    const float* W_ih2 = (const float*)d_in[5];
    const float* W_hh2 = (const float*)d_in[6];
    const float* b_ih2 = (const float*)d_in[7];
    const float* b_hh2 = (const float*)d_in[8];
    const float* W_lin = (const float*)d_in[9];
    const float* b_lin = (const float*)d_in[10];
    float* out = (float*)d_out;

    hipLaunchKernelGGL(lstm2_fp16u, dim3(NBLK), dim3(BT), 0, stream,
                       input, W_ih1, W_hh1, b_ih1, b_hh1,
                       W_ih2, W_hh2, b_ih2, b_hh2, W_lin, b_lin, out);
}

// Round 12
// 270.174 us; speedup vs baseline: 3.3357x; 1.0841x over previous
//
#include <hip/hip_runtime.h>

#define Hh 51
#define TT 512
#define MR 2            // batch rows per block (A-rows 0 and 4)
#define NBLK 256        // 512 / MR -> one block per CU, all 256 CUs
#define BT 512          // 8 waves: 0-3 layer-1 (+wave3: out-proj), 4-7 layer-2
#define SHR 80          // H row stride in fp16 elems (160B)
#define NIT 514         // 512 steps + 2 pipeline-drain iterations (even)
#define LOG2E 1.4426950408889634f

typedef _Float16 half8 __attribute__((ext_vector_type(8)));
typedef __attribute__((ext_vector_type(4))) float f32x4;

__device__ __forceinline__ float fexp2(float x){ return __builtin_amdgcn_exp2f(x); }
__device__ __forceinline__ float frcp(float x){ return __builtin_amdgcn_rcpf(x); }
__device__ __forceinline__ float sigm(float x){ return frcp(1.f + fexp2(-LOG2E*x)); }
__device__ __forceinline__ float ftanh(float x){ return 1.f - 2.f*frcp(1.f + fexp2(2.f*LOG2E*x)); }
__device__ __forceinline__ unsigned short h16bits(_Float16 h){
    union { _Float16 h; unsigned short u; } c; c.h = h; return c.u;
}
// pack float -> fp16 hi/lo pair in one uint (hi in low 16, lo in high 16)
__device__ __forceinline__ unsigned packhl(float v){
    _Float16 hi = (_Float16)v;
    _Float16 lo = (_Float16)(v - (float)hi);
    return (unsigned)h16bits(hi) | ((unsigned)h16bits(lo) << 16);
}

#define MFMAH(a,b,c) __builtin_amdgcn_mfma_f32_16x16x32_f16(a,b,c,0,0,0)

__global__ __launch_bounds__(BT, 2) void lstm2_fold(
    const float* __restrict__ input,   // [512,512]
    const float* __restrict__ W_ih1,   // [204]
    const float* __restrict__ W_hh1,   // [204,51]
    const float* __restrict__ b_ih1,
    const float* __restrict__ b_hh1,
    const float* __restrict__ W_ih2,   // [204,51]
    const float* __restrict__ W_hh2,   // [204,51]
    const float* __restrict__ b_ih2,
    const float* __restrict__ b_hh2,
    const float* __restrict__ W_lin,   // [51]
    const float* __restrict__ b_lin,   // [1]
    float* __restrict__ out)           // [512,512]
{
    __shared__ unsigned xsp[(TT+1)*MR];  // packed fp16 hi/lo x[t][m]
    __shared__ float ob[TT*MR];          // out[t][m]
    // h state, A-frag layout [m][k] fp16, double-buffered by parity.
    // Live A-rows: 0, 4. K-slots per row: 0..50 = h, 51 = 1.0, 52/53 = x_hi/x_lo, 54 = 1.0.
    __shared__ __align__(16) _Float16 H1[2][16*SHR];
    __shared__ __align__(16) _Float16 H2[2][16*SHR];

    const int tid  = threadIdx.x;
    const int wv   = tid >> 6;
    const int lane = tid & 63;
    const int quad = lane >> 4;
    const int n16  = lane & 15;
    const int row0 = blockIdx.x * MR;
    const bool g1  = (wv < 4);
    const bool w3  = (wv == 3);
    const int  w   = g1 ? wv : (wv - 4);       // wave index within group
    const int  l   = 13 * w + n16;             // hidden unit owned by this lane-column
    const bool valid = (n16 <= 12) && (l < Hh);
    const bool liveA = ((n16 & 11) == 0);      // n16 in {0,4}: the two live A-rows
    const bool updL  = (quad < MR) && valid;   // lanes doing the gate/state update
    const bool xw    = (wv == 0) && (n16 == 0) && (quad < MR);  // x-forward lanes
    const int  fo    = n16 * SHR + quad * 8;   // A-frag element offset (loop-invariant)
    const int  ho    = (quad * 4) * SHR + l;   // h store offset (rows 0 / 4)

    // ---- stage input rows as packed fp16 hi/lo (coalesced in t)
#pragma unroll
    for (int i = 0; i < MR; ++i) {
        int idx = i * BT + tid; int m = idx >> 9, t = idx & 511;
        xsp[t * MR + m] = packhl(input[(row0 + m) * TT + t]);
    }
    if (tid < MR) xsp[TT * MR + tid] = 0u;     // tail (x(512) read at n=511)
    // ---- zero h buffers (both parities; all rows)
    for (int i = tid; i < 2 * 16 * SHR / 2; i += BT) {
        ((int*)H1)[i] = 0; ((int*)H2)[i] = 0;
    }

    // ---- persistent weight B-fragments (fp16), gate-interleaved permutation:
    // tile gt (gate i,f,g,o), col c=n16  <->  weight row gt*51 + (13w+c)
    // K-columns 51..54 carry the affine epilogue: [bias_hi, wih, wih, bias_lo]
    half8 z8 = {0,0,0,0,0,0,0,0};
    half8 B1[4][2];                // W_hh1 (+bias1/wih slots)  (group 1)
    half8 B2[4][2], B3[4][2];      // W_ih2 (+bias2), W_hh2 (group 2)
    half8 Bout[2];                 // W_lin (+blin) column (wave 3)
    const f32x4 zc = (f32x4){0.f,0.f,0.f,0.f};   // persistent zero accumulator seed
#pragma unroll
    for (int gt = 0; gt < 4; ++gt) {
        int jrow = gt * Hh + l;
        float bias = 0.f, wih = 0.f;
        if (valid) {
            bias = g1 ? (b_ih1[jrow] + b_hh1[jrow]) : (b_ih2[jrow] + b_hh2[jrow]);
            wih  = g1 ? W_ih1[jrow] : 0.f;
        }
        _Float16 bhi = (_Float16)bias;
        _Float16 blo = (_Float16)(bias - (float)bhi);
        _Float16 wih_h = (_Float16)wih;
#pragma unroll
        for (int kt = 0; kt < 2; ++kt) {
            B1[gt][kt] = z8; B2[gt][kt] = z8; B3[gt][kt] = z8;
#pragma unroll
            for (int jj = 0; jj < 8; ++jj) {
                int k = kt * 32 + quad * 8 + jj;
                if (valid) {
                    if (g1) {
                        if (k < Hh)       B1[gt][kt][jj] = (_Float16)W_hh1[jrow * Hh + k];
                        else if (k == 51) B1[gt][kt][jj] = bhi;
                        else if (k == 52 || k == 53) B1[gt][kt][jj] = wih_h;
                        else if (k == 54) B1[gt][kt][jj] = blo;
                    } else {
                        if (k < Hh) {
                            B2[gt][kt][jj] = (_Float16)W_ih2[jrow * Hh + k];
                            B3[gt][kt][jj] = (_Float16)W_hh2[jrow * Hh + k];
                        } else if (k == 51) B2[gt][kt][jj] = bhi;
                        else if (k == 54)   B2[gt][kt][jj] = blo;
                    }
                }
            }
        }
    }
    {
        float blf = b_lin[0];
        _Float16 blhi = (_Float16)blf;
        _Float16 bllo = (_Float16)(blf - (float)blhi);
#pragma unroll
        for (int kt = 0; kt < 2; ++kt) {
            Bout[kt] = z8;
#pragma unroll
            for (int jj = 0; jj < 8; ++jj) {
                int k = kt * 32 + quad * 8 + jj;
                if (w3 && n16 == 0) {
                    if (k < Hh)       Bout[kt][jj] = (_Float16)W_lin[k];
                    else if (k == 51) Bout[kt][jj] = blhi;
                    else if (k == 54) Bout[kt][jj] = bllo;
                }
            }
        }
    }
    float cst = 0.f;   // cell state: quad0 lanes -> batch row 0, quad1 -> row 1 (unit l)

    // A-fragment registers persist; masked-out lanes keep zero.
    half8 f1a = z8, f1b = z8;      // h1 frags
    half8 f2a = z8, f2b = z8;      // h2 frags (g2 + wave3-out)

    __syncthreads();
    // ---- constant K-slots (after zeroing): rows 0,4; both parities; x(0) into parity 1
    if (tid < MR) {
        int r = tid * 4 * SHR;
        const unsigned one = (unsigned)h16bits((_Float16)1.0f);
#pragma unroll
        for (int p = 0; p < 2; ++p) {
            H1[p][r + 51] = (_Float16)1.0f;  H1[p][r + 54] = (_Float16)1.0f;
            H2[p][r + 51] = (_Float16)1.0f;  H2[p][r + 54] = (_Float16)1.0f;
        }
        *(unsigned*)&H1[1][r + 52] = xsp[tid];   // x(0) hi/lo for step 0 (reads parity 1)
        (void)one;
    }
    __syncthreads();

    // one pipeline step; pA/pB are compile-time literals at call sites
    auto stepfn = [&](int n, int pA, int pB) {
        if (g1) {
            if (w3 && n >= 2) {                // out-proj frags: h2(n-2)
                if (liveA) {
                    f2a = *(const half8*)&H2[pB][fo];
                    f2b = *(const half8*)&H2[pB][fo + 32];
                }
            }
            if (n < TT) {
                // ---- layer-1, time n: z1 = Whh1·[h1(n-1),1,x(n)]  (epilogue in K-slack)
                unsigned xn = xw ? xsp[(n + 1) * MR + quad] : 0u;   // x(n+1) forward
                if (liveA) {
                    f1a = *(const half8*)&H1[pA][fo];
                    f1b = *(const half8*)&H1[pA][fo + 32];
                }
                f32x4 ac[4];
#pragma unroll
                for (int gt = 0; gt < 4; ++gt) {
                    f32x4 a = MFMAH(f1a, B1[gt][0], zc);
                    a       = MFMAH(f1b, B1[gt][1], a);
                    ac[gt] = a;
                }
                if (updL) {
                    float ii = sigm(ac[0][0]), ff = sigm(ac[1][0]);
                    float gg = ftanh(ac[2][0]), oo = sigm(ac[3][0]);
                    cst = fmaf(ff, cst, ii * gg);
                    float h = oo * ftanh(cst);
                    H1[pB][ho] = (_Float16)h;
                }
                if (xw) *(unsigned*)&H1[pB][(quad * 4) * SHR + 52] = xn;
            }
            if (w3 && n >= 2) {
                // out(n-2) = W_lin·h2(n-2) + blin   (bias in K-slack)
                f32x4 ao = MFMAH(f2a, Bout[0], zc);
                ao       = MFMAH(f2b, Bout[1], ao);
                if (n16 == 0 && quad < MR) ob[(n - 2) * MR + quad] = ao[0];
            }
        } else if (n >= 1 && n <= TT) {
            // ---- layer-2, time n-1: z2 = Wih2·[h1(n-1),1] + Whh2·h2(n-2)
            if (liveA) {
                f1a = *(const half8*)&H1[pA][fo];
                f1b = *(const half8*)&H1[pA][fo + 32];
                f2a = *(const half8*)&H2[pB][fo];
                f2b = *(const half8*)&H2[pB][fo + 32];
            }
            f32x4 ac[4];
#pragma unroll
            for (int gt = 0; gt < 4; ++gt) {
                f32x4 a = MFMAH(f2a, B3[gt][0], zc);
                a       = MFMAH(f2b, B3[gt][1], a);
                a       = MFMAH(f1a, B2[gt][0], a);
                a       = MFMAH(f1b, B2[gt][1], a);
                ac[gt] = a;
            }
            if (updL) {
                float ii = sigm(ac[0][0]), ff = sigm(ac[1][0]);
                float gg = ftanh(ac[2][0]), oo = sigm(ac[3][0]);
                cst = fmaf(ff, cst, ii * gg);
                float h = oo * ftanh(cst);
                H2[pA][ho] = (_Float16)h;
            }
        }
        __syncthreads();   // publishes h1(n), x(n+1), h2(n-1) for iteration n+1
    };

    // unroll x2: parity literals fold all LDS addressing to base+constant
    for (int k2 = 0; k2 < NIT / 2; ++k2) {
        stepfn(2 * k2,     1, 0);
        stepfn(2 * k2 + 1, 0, 1);
    }

    // ---- flush outputs (coalesced in t)
#pragma unroll
    for (int i = 0; i < MR; ++i) {
        int idx = i * BT + tid; int m = idx >> 9, t = idx & 511;
        out[(row0 + m) * TT + t] = ob[t * MR + m];
    }
}

extern "C" void kernel_launch(void* const* d_in, const int* in_sizes, int n_in,
                              void* d_out, int out_size, void* d_ws, size_t ws_size,
                              hipStream_t stream) {
    const float* input = (const float*)d_in[0];
    const float* W_ih1 = (const float*)d_in[1];
    const float* W_hh1 = (const float*)d_in[2];
    const float* b_ih1 = (const float*)d_in[3];
    const float* b_hh1 = (const float*)d_in[4];
    const float* W_ih2 = (const float*)d_in[5];
    const float* W_hh2 = (const float*)d_in[6];
    const float* b_ih2 = (const float*)d_in[7];
    const float* b_hh2 = (const float*)d_in[8];
    const float* W_lin = (const float*)d_in[9];
    const float* b_lin = (const float*)d_in[10];
    float* out = (float*)d_out;

    hipLaunchKernelGGL(lstm2_fold, dim3(NBLK), dim3(BT), 0, stream,
                       input, W_ih1, W_hh1, b_ih1, b_hh1,
                       W_ih2, W_hh2, b_ih2, b_hh2, W_lin, b_lin, out);
}